// Round 8
// baseline (2051.842 us; speedup 1.0000x reference)
//
#include <hip/hip_runtime.h>
#include <hip/hip_bf16.h>

typedef __attribute__((ext_vector_type(4))) float f32x4;
typedef __attribute__((ext_vector_type(8))) short short8;
typedef __attribute__((ext_vector_type(4))) int i32x4;
typedef __attribute__((ext_vector_type(2))) unsigned int u32x2;
typedef __attribute__((ext_vector_type(4))) unsigned int u32x4;
typedef __attribute__((ext_vector_type(4))) unsigned short u16x4;

static __device__ __forceinline__ unsigned short f2bf(float f) {
  unsigned u = __builtin_bit_cast(unsigned, f);
  u = u + 0x7FFFu + ((u >> 16) & 1u);   // RNE
  return (unsigned short)(u >> 16);
}
static __device__ __forceinline__ float bf2f(unsigned short b) {
  unsigned u = ((unsigned)b) << 16;
  return __builtin_bit_cast(float, u);
}
static __device__ __forceinline__ float sigmoidf_fast(float x) {
  return __builtin_amdgcn_rcpf(1.f + __expf(-x));
}
static __device__ __forceinline__ float tanhf_fast(float x) {
  x = fminf(20.f, fmaxf(-20.f, x));
  float e = __expf(2.f * x);
  return (e - 1.f) * __builtin_amdgcn_rcpf(e + 1.f);
}
// packed bf16 pair: low16 = bf16(a), high16 = bf16(b)
static __device__ __forceinline__ unsigned cvt_pk_bf16(float a, float b) {
  unsigned d;
  asm volatile("v_cvt_pk_bf16_f32 %0, %1, %2" : "=v"(d) : "v"(a), "v"(b));
  return d;
}

// ---------------- cast f32 -> hi/lo bf16 pair (RNE hi) ----------------
__global__ void cast_split_kernel(const float* __restrict__ in,
                                  unsigned short* __restrict__ oh,
                                  unsigned short* __restrict__ ol, int n4) {
  int i = blockIdx.x * blockDim.x + threadIdx.x;
  if (i >= n4) return;
  f32x4 v = ((const f32x4*)in)[i];
  u16x4 h, l;
#pragma unroll
  for (int j = 0; j < 4; ++j) {
    unsigned short hb = f2bf(v[j]);
    h[j] = hb;
    l[j] = f2bf(v[j] - bf2f(hb));
  }
  ((u16x4*)oh)[i] = h;
  ((u16x4*)ol)[i] = l;
}

// ---------------- transpose + cast: (R,C) f32 -> (C,R) bf16 ----------------
__global__ void tcast_kernel(const float* __restrict__ in,
                             unsigned short* __restrict__ out, int R, int C) {
  int i = blockIdx.x * blockDim.x + threadIdx.x;
  if (i >= R * C) return;
  int r = i / C, c = i % C;
  out[(size_t)c * R + r] = f2bf(in[i]);
}

// ---------------- transpose + split cast: (R,C) f32 -> (C,R) hi/lo bf16 ----------------
__global__ void tcast_split_kernel(const float* __restrict__ in,
                                   unsigned short* __restrict__ oh,
                                   unsigned short* __restrict__ ol, int R, int C) {
  int i = blockIdx.x * blockDim.x + threadIdx.x;
  if (i >= R * C) return;
  int r = i / C, c = i % C;
  float v = in[i];
  unsigned short hb = f2bf(v);
  oh[(size_t)c * R + r] = hb;
  ol[(size_t)c * R + r] = f2bf(v - bf2f(hb));
}

// ---------------- f gate: one wave per token row (pure f32) ----------------
__global__ __launch_bounds__(256) void fgate_kernel(const float* __restrict__ x,
                                                    const float* __restrict__ Wf,
                                                    const float* __restrict__ bfv,
                                                    float* __restrict__ fbuf) {
  int wid = (blockIdx.x * blockDim.x + threadIdx.x) >> 6;  // token row 0..4095
  int lane = threadIdx.x & 63;
  const float* xr = x + (size_t)wid * 1024;
  float acc[8] = {0.f, 0.f, 0.f, 0.f, 0.f, 0.f, 0.f, 0.f};
#pragma unroll 4
  for (int it = 0; it < 16; ++it) {
    int d = it * 64 + lane;
    float xv = xr[d];
    f32x4 w0 = *(const f32x4*)(Wf + (size_t)d * 8);
    f32x4 w1 = *(const f32x4*)(Wf + (size_t)d * 8 + 4);
    acc[0] += xv * w0[0]; acc[1] += xv * w0[1];
    acc[2] += xv * w0[2]; acc[3] += xv * w0[3];
    acc[4] += xv * w1[0]; acc[5] += xv * w1[1];
    acc[6] += xv * w1[2]; acc[7] += xv * w1[3];
  }
#pragma unroll
  for (int n = 0; n < 8; ++n) {
#pragma unroll
    for (int m = 1; m < 64; m <<= 1) acc[n] += __shfl_xor(acc[n], m, 64);
  }
  if (lane == 0) {
#pragma unroll
    for (int n = 0; n < 8; ++n)
      fbuf[(size_t)wid * 8 + n] = sigmoidf_fast(acc[n] + bfv[n]);
  }
}

// ---------------- causal depthwise conv (KC=4) + SiLU, all 3 tensors ----------------
__global__ void conv_silu_kernel(const float* __restrict__ pre,
                                 const float* __restrict__ cwq,
                                 const float* __restrict__ cwk,
                                 const float* __restrict__ cwv,
                                 float* __restrict__ outb) {
  int i = blockIdx.x * blockDim.x + threadIdx.x;  // B*L*512
  int which = blockIdx.y;
  const float* cw = (which == 0) ? cwq : (which == 1) ? cwk : cwv;
  const float* p = pre + (size_t)which * 2097152 + i;
  int c = i & 511;
  int l = (i >> 9) & 1023;
  float w0 = cw[c * 4 + 0], w1 = cw[c * 4 + 1], w2 = cw[c * 4 + 2], w3 = cw[c * 4 + 3];
  float acc = w3 * p[0];
  if (l >= 1) acc += w2 * p[-512];
  if (l >= 2) acc += w1 * p[-1024];
  if (l >= 3) acc += w0 * p[-1536];
  outb[(size_t)which * 2097152 + i] = acc * sigmoidf_fast(acc);
}

// ---------------- plain bf16 MFMA GEMM: C(M,Nd) = A * Bt^T ----------------
__global__ __launch_bounds__(256) void gemm_bf16_kernel(
    const unsigned short* __restrict__ A, const unsigned short* __restrict__ Bt,
    float* __restrict__ C, int Kd, int Nd, size_t BtStride, size_t CStride) {
  __shared__ unsigned short Ash[128][40];
  __shared__ unsigned short Bsh[128][40];
  const int tid = threadIdx.x;
  const int wave = tid >> 6, lane = tid & 63;
  const int g = lane >> 4, lr = lane & 15;
  const int m0 = blockIdx.x * 128, n0 = blockIdx.y * 128;
  const unsigned short* Bz = Bt + blockIdx.z * BtStride;
  float* Cz = C + blockIdx.z * CStride;
  const int wm = (wave >> 1) * 64, wn = (wave & 1) * 64;

  f32x4 acc[4][4];
#pragma unroll
  for (int a = 0; a < 4; ++a)
#pragma unroll
    for (int bq = 0; bq < 4; ++bq) acc[a][bq] = (f32x4){0.f, 0.f, 0.f, 0.f};

  for (int k0 = 0; k0 < Kd; k0 += 32) {
#pragma unroll
    for (int it = 0; it < 2; ++it) {
      int cch = tid + 256 * it;
      int r = cch >> 2, cc = cch & 3;
      *(i32x4*)&Ash[r][cc * 8] = *(const i32x4*)(A + (size_t)(m0 + r) * Kd + k0 + cc * 8);
      *(i32x4*)&Bsh[r][cc * 8] = *(const i32x4*)(Bz + (size_t)(n0 + r) * Kd + k0 + cc * 8);
    }
    __syncthreads();
    short8 af[4], bfr[4];
#pragma unroll
    for (int mt = 0; mt < 4; ++mt) af[mt] = *(const short8*)&Ash[wm + mt * 16 + lr][g * 8];
#pragma unroll
    for (int nt = 0; nt < 4; ++nt) bfr[nt] = *(const short8*)&Bsh[wn + nt * 16 + lr][g * 8];
#pragma unroll
    for (int mt = 0; mt < 4; ++mt)
#pragma unroll
      for (int nt = 0; nt < 4; ++nt)
        acc[mt][nt] = __builtin_amdgcn_mfma_f32_16x16x32_bf16(af[mt], bfr[nt], acc[mt][nt], 0, 0, 0);
    __syncthreads();
  }
#pragma unroll
  for (int mt = 0; mt < 4; ++mt)
#pragma unroll
    for (int nt = 0; nt < 4; ++nt)
#pragma unroll
      for (int r = 0; r < 4; ++r) {
        int m = m0 + wm + mt * 16 + g * 4 + r;
        int n = n0 + wn + nt * 16 + lr;
        Cz[(size_t)m * Nd + n] = acc[mt][nt][r];
      }
}

// ---------------- split-bf16 (3-term f32-emulation) GEMM ----------------
__global__ __launch_bounds__(256) void gemm_split_kernel(
    const unsigned short* __restrict__ Ah, const unsigned short* __restrict__ Al,
    const unsigned short* __restrict__ Bth, const unsigned short* __restrict__ Btl,
    float* __restrict__ C, int Kd, int Nd, size_t BtStride, size_t CStride) {
  __shared__ unsigned short AshH[128][40];
  __shared__ unsigned short AshL[128][40];
  __shared__ unsigned short BshH[128][40];
  __shared__ unsigned short BshL[128][40];
  const int tid = threadIdx.x;
  const int wave = tid >> 6, lane = tid & 63;
  const int g = lane >> 4, lr = lane & 15;
  const int m0 = blockIdx.x * 128, n0 = blockIdx.y * 128;
  const unsigned short* Bzh = Bth + blockIdx.z * BtStride;
  const unsigned short* Bzl = Btl + blockIdx.z * BtStride;
  float* Cz = C + blockIdx.z * CStride;
  const int wm = (wave >> 1) * 64, wn = (wave & 1) * 64;

  f32x4 acc[4][4];
#pragma unroll
  for (int a = 0; a < 4; ++a)
#pragma unroll
    for (int bq = 0; bq < 4; ++bq) acc[a][bq] = (f32x4){0.f, 0.f, 0.f, 0.f};

  for (int k0 = 0; k0 < Kd; k0 += 32) {
#pragma unroll
    for (int it = 0; it < 2; ++it) {
      int cch = tid + 256 * it;
      int r = cch >> 2, cc = cch & 3;
      size_t ao = (size_t)(m0 + r) * Kd + k0 + cc * 8;
      size_t bo = (size_t)(n0 + r) * Kd + k0 + cc * 8;
      *(i32x4*)&AshH[r][cc * 8] = *(const i32x4*)(Ah + ao);
      *(i32x4*)&AshL[r][cc * 8] = *(const i32x4*)(Al + ao);
      *(i32x4*)&BshH[r][cc * 8] = *(const i32x4*)(Bzh + bo);
      *(i32x4*)&BshL[r][cc * 8] = *(const i32x4*)(Bzl + bo);
    }
    __syncthreads();
    short8 afh[4], afl[4], bfh[4], bfl[4];
#pragma unroll
    for (int mt = 0; mt < 4; ++mt) {
      afh[mt] = *(const short8*)&AshH[wm + mt * 16 + lr][g * 8];
      afl[mt] = *(const short8*)&AshL[wm + mt * 16 + lr][g * 8];
    }
#pragma unroll
    for (int nt = 0; nt < 4; ++nt) {
      bfh[nt] = *(const short8*)&BshH[wn + nt * 16 + lr][g * 8];
      bfl[nt] = *(const short8*)&BshL[wn + nt * 16 + lr][g * 8];
    }
#pragma unroll
    for (int mt = 0; mt < 4; ++mt)
#pragma unroll
      for (int nt = 0; nt < 4; ++nt) {
        f32x4 a = acc[mt][nt];
        a = __builtin_amdgcn_mfma_f32_16x16x32_bf16(afl[mt], bfh[nt], a, 0, 0, 0);
        a = __builtin_amdgcn_mfma_f32_16x16x32_bf16(afh[mt], bfl[nt], a, 0, 0, 0);
        a = __builtin_amdgcn_mfma_f32_16x16x32_bf16(afh[mt], bfh[nt], a, 0, 0, 0);
        acc[mt][nt] = a;
      }
    __syncthreads();
  }
#pragma unroll
  for (int mt = 0; mt < 4; ++mt)
#pragma unroll
    for (int nt = 0; nt < 4; ++nt)
#pragma unroll
      for (int r = 0; r < 4; ++r) {
        int m = m0 + wm + mt * 16 + g * 4 + r;
        int n = n0 + wn + nt * 16 + lr;
        Cz[(size_t)m * Nd + n] = acc[mt][nt][r];
      }
}

// ---------------- recurrent scan: 2 chains per 1024-thr block ----------------
// Round-7-verified per-chain skeleton (single Hh/Hl, 2 barriers/step, y after write).
// Round-8 deltas:
//   (1) two (b,n) chains per block (half = tid>>9): 4 waves/SIMD latency hiding.
//   (2) Ht col swizzle adds ^(((k>>3)&3)<<3) on the v index: y-reads 8-way -> 2-way.
//   (3) v_cvt_pk_bf16_f32 packing, 2x6 chained MFMAs, exp2-fused tanh.
// Row planes: row k at byte k*128, elem v at byte (2v) ^ ((k&7)<<4).
// Ht: byte = k*256 + ((4*(v ^ (((k>>3)&3)<<3))) ^ ((k&7)<<5)), u32 = hi<<16|lo.
__global__ __launch_bounds__(1024) void scan_kernel(
    const float* __restrict__ qbuf, const float* __restrict__ kbuf,
    const float* __restrict__ vbuf, const float* __restrict__ fbuf,
    const float* __restrict__ W, unsigned short* __restrict__ yb,
    float* __restrict__ Hout) {
  const int tid = threadIdx.x;
  const int half = tid >> 9, t9 = tid & 511;
  const int wave9 = t9 >> 6, lane = tid & 63;
  const int g = lane >> 4, lr = lane & 15;
  const int wk = wave9 & 3, wh = wave9 >> 2;
  const int b = blockIdx.x >> 2;
  const int n = ((blockIdx.x & 3) << 1) | half;
  const int kq = wk * 16 + lr;
  const int swz = (kq & 7) << 4;

  __shared__ unsigned short Hh[2][4096];   // 2 x 8 KB hi plane
  __shared__ unsigned short Hl[2][4096];   // 2 x 8 KB lo plane
  __shared__ unsigned Ht[2][4096];         // 2 x 16 KB packed copy
  __shared__ float stage[2][2][16][192];   // [chain][buf] 48 KB
  __shared__ float fs[2][2][16];
  __shared__ unsigned short yst[2][1024];  // 4 KB

  for (int i = t9; i < 2048; i += 512) {
    ((unsigned int*)Hh[half])[i] = 0u;
    ((unsigned int*)Hl[half])[i] = 0u;
  }

  // W^T split hi/lo fragments (RNE hi)
  const float* Wn = W + (size_t)n * 4096;
  short8 Af[2][2], Alw[2][2];
#pragma unroll
  for (int u = 0; u < 2; ++u)
#pragma unroll
    for (int s = 0; s < 2; ++s) {
      int wcol = (wh * 2 + u) * 16 + lr;
      short8 ah, al;
#pragma unroll
      for (int j = 0; j < 8; ++j) {
        float wv = Wn[(size_t)(s * 32 + g * 8 + j) * 64 + wcol];
        unsigned short hb = f2bf(wv);
        ah[j] = (short)hb;
        al[j] = (short)f2bf(wv - bf2f(hb));
      }
      Af[u][s] = ah; Alw[u][s] = al;
    }

  // y-phase geometry: column vy, 8 k-rows at k0y; xor-8/16/32 covers all 64 k
  const int vy = wave9 * 8 + (lane & 7);
  const int k0y = 32 * (lr >> 3) + 8 * g;

  // Ht addresses (col swizzle: v ^ (((k>>3)&3)<<3), row swizzle (k&7)<<5)
  char* Htb = (char*)Ht[half];
  const int kg2 = (kq >> 3) & 3;
  char* htwA = Htb + kq * 256 +
               ((4 * ((((2 * wh + 0) * 16 + 4 * g)) ^ (kg2 << 3))) ^ ((kq & 7) << 5));
  char* htwB = Htb + kq * 256 +
               ((4 * ((((2 * wh + 1) * 16 + 4 * g)) ^ (kg2 << 3))) ^ ((kq & 7) << 5));
  const char* htR[8];
#pragma unroll
  for (int j = 0; j < 8; ++j)
    htR[j] = Htb + (k0y + j) * 256 + ((4 * (vy ^ (g << 3))) ^ (j << 5));

  // chunk staging: per chain, 16 steps x 192 floats = 768 f32x4 by 512 threads
  auto stage_chunk = [&](int c, int buf) {
#pragma unroll
    for (int i = 0; i < 2; ++i) {
      int fi = t9 + i * 512;
      if (fi < 768) {
        int st = fi / 48, un = fi - st * 48;
        const float* basep = (un < 16) ? qbuf : (un < 32) ? kbuf : vbuf;
        f32x4 val = *(const f32x4*)(basep + (size_t)(b * 1024 + c * 16 + st) * 512 +
                                    n * 64 + (un & 15) * 4);
        *(f32x4*)&stage[half][buf][st][un * 4] = val;
      }
    }
    if (t9 < 16) fs[half][buf][t9] = fbuf[(size_t)(b * 1024 + c * 16 + t9) * 8 + n];
  };

  f32x4 HA = (f32x4){0.f, 0.f, 0.f, 0.f};   // H[kq][(2wh+0)*16+4g+r]
  f32x4 HB = (f32x4){0.f, 0.f, 0.f, 0.f};   // H[kq][(2wh+1)*16+4g+r]
  int sb = 0;

  stage_chunk(0, 0);
  __syncthreads();

  const f32x4 zf = (f32x4){0.f, 0.f, 0.f, 0.f};
  const char* hrh = (const char*)(Hh[half] + kq * 64);
  const char* hrl = (const char*)(Hl[half] + kq * 64);
  char* hwh = (char*)(Hh[half] + kq * 64);
  char* hwl = (char*)(Hl[half] + kq * 64);
  const int bo0 = (16 * g) ^ swz;
  const int bo1 = (64 + 16 * g) ^ swz;
  const int wo0 = ((2 * wh + 0) * 32 + 8 * g) ^ swz;
  const int wo1 = ((2 * wh + 1) * 32 + 8 * g) ^ swz;
  const float K2L2E = 2.885390081777927f;   // 2*log2(e)

  for (int c = 0; c < 64; ++c) {
    if (c < 63) stage_chunk(c + 1, sb ^ 1);
    for (int tl = 0; tl < 16; ++tl) {
      const float* srow = &stage[half][sb][tl][0];

      short8 Bh0 = *(const short8*)(hrh + bo0);
      short8 Bh1 = *(const short8*)(hrh + bo1);
      short8 Bl0 = *(const short8*)(hrl + bo0);
      short8 Bl1 = *(const short8*)(hrl + bo1);

      // 12 MFMAs: 3-term split, 2 chains of 6 (small terms first)
      f32x4 a0 = __builtin_amdgcn_mfma_f32_16x16x32_bf16(Alw[0][0], Bh0, zf, 0, 0, 0);
      f32x4 a1 = __builtin_amdgcn_mfma_f32_16x16x32_bf16(Alw[1][0], Bh0, zf, 0, 0, 0);
      a0 = __builtin_amdgcn_mfma_f32_16x16x32_bf16(Alw[0][1], Bh1, a0, 0, 0, 0);
      a1 = __builtin_amdgcn_mfma_f32_16x16x32_bf16(Alw[1][1], Bh1, a1, 0, 0, 0);
      a0 = __builtin_amdgcn_mfma_f32_16x16x32_bf16(Af[0][1], Bl1, a0, 0, 0, 0);
      a1 = __builtin_amdgcn_mfma_f32_16x16x32_bf16(Af[1][1], Bl1, a1, 0, 0, 0);
      a0 = __builtin_amdgcn_mfma_f32_16x16x32_bf16(Af[0][0], Bl0, a0, 0, 0, 0);
      a1 = __builtin_amdgcn_mfma_f32_16x16x32_bf16(Af[1][0], Bl0, a1, 0, 0, 0);
      a0 = __builtin_amdgcn_mfma_f32_16x16x32_bf16(Af[0][1], Bh1, a0, 0, 0, 0);
      a1 = __builtin_amdgcn_mfma_f32_16x16x32_bf16(Af[1][1], Bh1, a1, 0, 0, 0);
      a0 = __builtin_amdgcn_mfma_f32_16x16x32_bf16(Af[0][0], Bh0, a0, 0, 0, 0);
      a1 = __builtin_amdgcn_mfma_f32_16x16x32_bf16(Af[1][0], Bh0, a1, 0, 0, 0);

      float kval = srow[64 + kq];
      f32x4 vv0 = *(const f32x4*)(srow + 128 + (2 * wh + 0) * 16 + 4 * g);
      f32x4 vv1 = *(const f32x4*)(srow + 128 + (2 * wh + 1) * 16 + 4 * g);
      float fc = fs[half][sb][tl];

      // tanh (exp2-fused, overflow-safe) + gate blend
#pragma unroll
      for (int r = 0; r < 4; ++r) {
        float arg0 = fmaf(kval, vv0[r], a0[r]);
        float c0 = fmaf(-2.f, __builtin_amdgcn_rcpf(1.f + __builtin_amdgcn_exp2f(arg0 * K2L2E)), 1.f);
        HA[r] = fmaf(fc, HA[r] - c0, c0);
        float arg1 = fmaf(kval, vv1[r], a1[r]);
        float c1 = fmaf(-2.f, __builtin_amdgcn_rcpf(1.f + __builtin_amdgcn_exp2f(arg1 * K2L2E)), 1.f);
        HB[r] = fmaf(fc, HB[r] - c1, c1);
      }

      __syncthreads();  // B1: all H_t reads done

      {  // pack via cvt_pk; write row-major hi/lo + packed Ht
        unsigned ph0 = cvt_pk_bf16(HA[0], HA[1]);
        unsigned ph1 = cvt_pk_bf16(HA[2], HA[3]);
        float r0 = HA[0] - __builtin_bit_cast(float, ph0 << 16);
        float r1 = HA[1] - __builtin_bit_cast(float, ph0 & 0xFFFF0000u);
        float r2 = HA[2] - __builtin_bit_cast(float, ph1 << 16);
        float r3 = HA[3] - __builtin_bit_cast(float, ph1 & 0xFFFF0000u);
        unsigned pl0 = cvt_pk_bf16(r0, r1);
        unsigned pl1 = cvt_pk_bf16(r2, r3);
        *(u32x2*)(hwh + wo0) = (u32x2){ph0, ph1};
        *(u32x2*)(hwl + wo0) = (u32x2){pl0, pl1};
        u32x4 hta = {__builtin_amdgcn_perm(ph0, pl0, 0x05040100u),
                     __builtin_amdgcn_perm(ph0, pl0, 0x07060302u),
                     __builtin_amdgcn_perm(ph1, pl1, 0x05040100u),
                     __builtin_amdgcn_perm(ph1, pl1, 0x07060302u)};
        *(u32x4*)htwA = hta;

        unsigned qh0 = cvt_pk_bf16(HB[0], HB[1]);
        unsigned qh1 = cvt_pk_bf16(HB[2], HB[3]);
        float s0 = HB[0] - __builtin_bit_cast(float, qh0 << 16);
        float s1 = HB[1] - __builtin_bit_cast(float, qh0 & 0xFFFF0000u);
        float s2 = HB[2] - __builtin_bit_cast(float, qh1 << 16);
        float s3 = HB[3] - __builtin_bit_cast(float, qh1 & 0xFFFF0000u);
        unsigned ql0 = cvt_pk_bf16(s0, s1);
        unsigned ql1 = cvt_pk_bf16(s2, s3);
        *(u32x2*)(hwh + wo1) = (u32x2){qh0, qh1};
        *(u32x2*)(hwl + wo1) = (u32x2){ql0, ql1};
        u32x4 htb = {__builtin_amdgcn_perm(qh0, ql0, 0x05040100u),
                     __builtin_amdgcn_perm(qh0, ql0, 0x07060302u),
                     __builtin_amdgcn_perm(qh1, ql1, 0x05040100u),
                     __builtin_amdgcn_perm(qh1, ql1, 0x07060302u)};
        *(u32x4*)htwB = htb;
      }

      __syncthreads();  // B2: H planes = H_{t+1}

      // y_t = q_t . H_{t+1} from packed Ht
      {
        f32x4 qy0 = *(const f32x4*)(srow + k0y);
        f32x4 qy1 = *(const f32x4*)(srow + k0y + 4);
        float ys = 0.f;
#pragma unroll
        for (int j = 0; j < 8; ++j) {
          unsigned uu = *(const unsigned*)htR[j];
          float hv = __builtin_bit_cast(float, uu & 0xFFFF0000u) +
                     __builtin_bit_cast(float, uu << 16);
          float qv = (j < 4) ? qy0[j] : qy1[j - 4];
          ys += qv * hv;
        }
        ys += __shfl_xor(ys, 8, 64);
        ys += __shfl_xor(ys, 16, 64);
        ys += __shfl_xor(ys, 32, 64);
        if (lane < 8) yst[half][tl * 64 + vy] = f2bf(ys);
      }
    }

    __syncthreads();  // yst complete for this chunk
    {  // flush y chunk: per chain 512 threads x one u32 coalesced
      int tl2 = t9 >> 5, pv = (t9 & 31) << 1;
      unsigned val = ((const unsigned*)yst[half])[t9];
      *(unsigned*)(yb + (size_t)(b * 1024 + c * 16 + tl2) * 512 + n * 64 + pv) = val;
    }
    sb ^= 1;
  }

  // H_final (f32 master)
  float* Ho = Hout + (size_t)(b * 8 + n) * 4096;
  *(f32x4*)&Ho[(size_t)kq * 64 + (wh * 2 + 0) * 16 + g * 4] = HA;
  *(f32x4*)&Ho[(size_t)kq * 64 + (wh * 2 + 1) * 16 + g * 4] = HB;
}

// ---------------- launch ----------------
extern "C" void kernel_launch(void* const* d_in, const int* in_sizes, int n_in,
                              void* d_out, int out_size, void* d_ws, size_t ws_size,
                              hipStream_t stream) {
  const float* x   = (const float*)d_in[0];
  const float* Wq  = (const float*)d_in[1];
  const float* Wk  = (const float*)d_in[2];
  const float* Wv  = (const float*)d_in[3];
  const float* Wf  = (const float*)d_in[4];
  const float* bfv = (const float*)d_in[5];
  const float* cwq = (const float*)d_in[6];
  const float* cwk = (const float*)d_in[7];
  const float* cwv = (const float*)d_in[8];
  const float* W   = (const float*)d_in[9];
  const float* Wo  = (const float*)d_in[10];
  float* outp = (float*)d_out;

  char* ws = (char*)d_ws;
  size_t off = 0;
  auto alloc = [&](size_t bytes) {
    char* pp = ws + off;
    off = (off + bytes + 255) & ~(size_t)255;
    return pp;
  };
  unsigned short* xbh  = (unsigned short*)alloc((size_t)4194304 * 2);
  unsigned short* xbl  = (unsigned short*)alloc((size_t)4194304 * 2);
  unsigned short* wtbh = (unsigned short*)alloc((size_t)3 * 524288 * 2);
  unsigned short* wtbl = (unsigned short*)alloc((size_t)3 * 524288 * 2);
  float* pre  = (float*)alloc((size_t)3 * 2097152 * 4);
  float* qkv  = (float*)alloc((size_t)3 * 2097152 * 4);
  float* fbuf = (float*)alloc((size_t)32768 * 4);
  unsigned short* yb  = (unsigned short*)alloc((size_t)2097152 * 2);
  unsigned short* wot = (unsigned short*)alloc((size_t)524288 * 2);

  // casts / transposes (split hi/lo for the amplified paths)
  cast_split_kernel<<<4096, 256, 0, stream>>>(x, xbh, xbl, 1048576);
  tcast_split_kernel<<<2048, 256, 0, stream>>>(Wq, wtbh, wtbl, 1024, 512);
  tcast_split_kernel<<<2048, 256, 0, stream>>>(Wk, wtbh + 524288, wtbl + 524288, 1024, 512);
  tcast_split_kernel<<<2048, 256, 0, stream>>>(Wv, wtbh + 2 * 524288, wtbl + 2 * 524288, 1024, 512);
  // gate
  fgate_kernel<<<1024, 256, 0, stream>>>(x, Wf, bfv, fbuf);
  // q pre-activation: plain bf16 (un-amplified path)
  dim3 gq(32, 4, 1);
  gemm_bf16_kernel<<<gq, 256, 0, stream>>>(xbh, wtbh, pre, 1024, 512,
                                           (size_t)0, (size_t)0);
  // k,v pre-activations: split-bf16 (amplified path)
  dim3 gkv(32, 4, 2);
  gemm_split_kernel<<<gkv, 256, 0, stream>>>(xbh, xbl, wtbh + 524288, wtbl + 524288,
                                             pre + 2097152, 1024, 512,
                                             (size_t)524288, (size_t)2097152);
  // conv + silu (all three in one launch)
  dim3 gc(8192, 3, 1);
  conv_silu_kernel<<<gc, 256, 0, stream>>>(pre, cwq, cwk, cwv, qkv);
  // recurrent scan: 16 blocks x 1024 threads, 2 chains per block
  scan_kernel<<<16, 1024, 0, stream>>>(qkv, qkv + 2097152, qkv + 2 * 2097152, fbuf, W,
                                       yb, outp + 4194304);
  // output projection
  tcast_kernel<<<2048, 256, 0, stream>>>(Wo, wot, 512, 1024);
  dim3 g2(32, 8, 1);
  gemm_bf16_kernel<<<g2, 256, 0, stream>>>(yb, wot, outp, 512, 1024, (size_t)0, (size_t)0);
}

// Round 9
// 1591.507 us; speedup vs baseline: 1.2892x; 1.2892x over previous
//
#include <hip/hip_runtime.h>
#include <hip/hip_bf16.h>

typedef __attribute__((ext_vector_type(4))) float f32x4;
typedef __attribute__((ext_vector_type(8))) short short8;
typedef __attribute__((ext_vector_type(4))) int i32x4;
typedef __attribute__((ext_vector_type(2))) unsigned int u32x2;
typedef __attribute__((ext_vector_type(4))) unsigned short u16x4;

static __device__ __forceinline__ unsigned short f2bf(float f) {
  unsigned u = __builtin_bit_cast(unsigned, f);
  u = u + 0x7FFFu + ((u >> 16) & 1u);   // RNE
  return (unsigned short)(u >> 16);
}
static __device__ __forceinline__ float bf2f(unsigned short b) {
  unsigned u = ((unsigned)b) << 16;
  return __builtin_bit_cast(float, u);
}
static __device__ __forceinline__ float sigmoidf_fast(float x) {
  return __builtin_amdgcn_rcpf(1.f + __expf(-x));
}
// packed bf16 pair: low16 = bf16(a), high16 = bf16(b)
static __device__ __forceinline__ unsigned cvt_pk_bf16(float a, float b) {
  unsigned d;
  asm volatile("v_cvt_pk_bf16_f32 %0, %1, %2" : "=v"(d) : "v"(a), "v"(b));
  return d;
}

// ---------------- cast f32 -> hi/lo bf16 pair (RNE hi) ----------------
__global__ void cast_split_kernel(const float* __restrict__ in,
                                  unsigned short* __restrict__ oh,
                                  unsigned short* __restrict__ ol, int n4) {
  int i = blockIdx.x * blockDim.x + threadIdx.x;
  if (i >= n4) return;
  f32x4 v = ((const f32x4*)in)[i];
  u16x4 h, l;
#pragma unroll
  for (int j = 0; j < 4; ++j) {
    unsigned short hb = f2bf(v[j]);
    h[j] = hb;
    l[j] = f2bf(v[j] - bf2f(hb));
  }
  ((u16x4*)oh)[i] = h;
  ((u16x4*)ol)[i] = l;
}

// ---------------- transpose + cast: (R,C) f32 -> (C,R) bf16 ----------------
__global__ void tcast_kernel(const float* __restrict__ in,
                             unsigned short* __restrict__ out, int R, int C) {
  int i = blockIdx.x * blockDim.x + threadIdx.x;
  if (i >= R * C) return;
  int r = i / C, c = i % C;
  out[(size_t)c * R + r] = f2bf(in[i]);
}

// ---------------- transpose + split cast: (R,C) f32 -> (C,R) hi/lo bf16 ----------------
__global__ void tcast_split_kernel(const float* __restrict__ in,
                                   unsigned short* __restrict__ oh,
                                   unsigned short* __restrict__ ol, int R, int C) {
  int i = blockIdx.x * blockDim.x + threadIdx.x;
  if (i >= R * C) return;
  int r = i / C, c = i % C;
  float v = in[i];
  unsigned short hb = f2bf(v);
  oh[(size_t)c * R + r] = hb;
  ol[(size_t)c * R + r] = f2bf(v - bf2f(hb));
}

// ---------------- f gate: one wave per token row (pure f32) ----------------
__global__ __launch_bounds__(256) void fgate_kernel(const float* __restrict__ x,
                                                    const float* __restrict__ Wf,
                                                    const float* __restrict__ bfv,
                                                    float* __restrict__ fbuf) {
  int wid = (blockIdx.x * blockDim.x + threadIdx.x) >> 6;  // token row 0..4095
  int lane = threadIdx.x & 63;
  const float* xr = x + (size_t)wid * 1024;
  float acc[8] = {0.f, 0.f, 0.f, 0.f, 0.f, 0.f, 0.f, 0.f};
#pragma unroll 4
  for (int it = 0; it < 16; ++it) {
    int d = it * 64 + lane;
    float xv = xr[d];
    f32x4 w0 = *(const f32x4*)(Wf + (size_t)d * 8);
    f32x4 w1 = *(const f32x4*)(Wf + (size_t)d * 8 + 4);
    acc[0] += xv * w0[0]; acc[1] += xv * w0[1];
    acc[2] += xv * w0[2]; acc[3] += xv * w0[3];
    acc[4] += xv * w1[0]; acc[5] += xv * w1[1];
    acc[6] += xv * w1[2]; acc[7] += xv * w1[3];
  }
#pragma unroll
  for (int n = 0; n < 8; ++n) {
#pragma unroll
    for (int m = 1; m < 64; m <<= 1) acc[n] += __shfl_xor(acc[n], m, 64);
  }
  if (lane == 0) {
#pragma unroll
    for (int n = 0; n < 8; ++n)
      fbuf[(size_t)wid * 8 + n] = sigmoidf_fast(acc[n] + bfv[n]);
  }
}

// ---------------- causal depthwise conv (KC=4) + SiLU, all 3 tensors ----------------
__global__ void conv_silu_kernel(const float* __restrict__ pre,
                                 const float* __restrict__ cwq,
                                 const float* __restrict__ cwk,
                                 const float* __restrict__ cwv,
                                 float* __restrict__ outb) {
  int i = blockIdx.x * blockDim.x + threadIdx.x;  // B*L*512
  int which = blockIdx.y;
  const float* cw = (which == 0) ? cwq : (which == 1) ? cwk : cwv;
  const float* p = pre + (size_t)which * 2097152 + i;
  int c = i & 511;
  int l = (i >> 9) & 1023;
  float w0 = cw[c * 4 + 0], w1 = cw[c * 4 + 1], w2 = cw[c * 4 + 2], w3 = cw[c * 4 + 3];
  float acc = w3 * p[0];
  if (l >= 1) acc += w2 * p[-512];
  if (l >= 2) acc += w1 * p[-1024];
  if (l >= 3) acc += w0 * p[-1536];
  outb[(size_t)which * 2097152 + i] = acc * sigmoidf_fast(acc);
}

// ---------------- plain bf16 MFMA GEMM: C(M,Nd) = A * Bt^T ----------------
__global__ __launch_bounds__(256) void gemm_bf16_kernel(
    const unsigned short* __restrict__ A, const unsigned short* __restrict__ Bt,
    float* __restrict__ C, int Kd, int Nd, size_t BtStride, size_t CStride) {
  __shared__ unsigned short Ash[128][40];
  __shared__ unsigned short Bsh[128][40];
  const int tid = threadIdx.x;
  const int wave = tid >> 6, lane = tid & 63;
  const int g = lane >> 4, lr = lane & 15;
  const int m0 = blockIdx.x * 128, n0 = blockIdx.y * 128;
  const unsigned short* Bz = Bt + blockIdx.z * BtStride;
  float* Cz = C + blockIdx.z * CStride;
  const int wm = (wave >> 1) * 64, wn = (wave & 1) * 64;

  f32x4 acc[4][4];
#pragma unroll
  for (int a = 0; a < 4; ++a)
#pragma unroll
    for (int bq = 0; bq < 4; ++bq) acc[a][bq] = (f32x4){0.f, 0.f, 0.f, 0.f};

  for (int k0 = 0; k0 < Kd; k0 += 32) {
#pragma unroll
    for (int it = 0; it < 2; ++it) {
      int cch = tid + 256 * it;
      int r = cch >> 2, cc = cch & 3;
      *(i32x4*)&Ash[r][cc * 8] = *(const i32x4*)(A + (size_t)(m0 + r) * Kd + k0 + cc * 8);
      *(i32x4*)&Bsh[r][cc * 8] = *(const i32x4*)(Bz + (size_t)(n0 + r) * Kd + k0 + cc * 8);
    }
    __syncthreads();
    short8 af[4], bfr[4];
#pragma unroll
    for (int mt = 0; mt < 4; ++mt) af[mt] = *(const short8*)&Ash[wm + mt * 16 + lr][g * 8];
#pragma unroll
    for (int nt = 0; nt < 4; ++nt) bfr[nt] = *(const short8*)&Bsh[wn + nt * 16 + lr][g * 8];
#pragma unroll
    for (int mt = 0; mt < 4; ++mt)
#pragma unroll
      for (int nt = 0; nt < 4; ++nt)
        acc[mt][nt] = __builtin_amdgcn_mfma_f32_16x16x32_bf16(af[mt], bfr[nt], acc[mt][nt], 0, 0, 0);
    __syncthreads();
  }
#pragma unroll
  for (int mt = 0; mt < 4; ++mt)
#pragma unroll
    for (int nt = 0; nt < 4; ++nt)
#pragma unroll
      for (int r = 0; r < 4; ++r) {
        int m = m0 + wm + mt * 16 + g * 4 + r;
        int n = n0 + wn + nt * 16 + lr;
        Cz[(size_t)m * Nd + n] = acc[mt][nt][r];
      }
}

// ---------------- split-bf16 (3-term f32-emulation) GEMM ----------------
__global__ __launch_bounds__(256) void gemm_split_kernel(
    const unsigned short* __restrict__ Ah, const unsigned short* __restrict__ Al,
    const unsigned short* __restrict__ Bth, const unsigned short* __restrict__ Btl,
    float* __restrict__ C, int Kd, int Nd, size_t BtStride, size_t CStride) {
  __shared__ unsigned short AshH[128][40];
  __shared__ unsigned short AshL[128][40];
  __shared__ unsigned short BshH[128][40];
  __shared__ unsigned short BshL[128][40];
  const int tid = threadIdx.x;
  const int wave = tid >> 6, lane = tid & 63;
  const int g = lane >> 4, lr = lane & 15;
  const int m0 = blockIdx.x * 128, n0 = blockIdx.y * 128;
  const unsigned short* Bzh = Bth + blockIdx.z * BtStride;
  const unsigned short* Bzl = Btl + blockIdx.z * BtStride;
  float* Cz = C + blockIdx.z * CStride;
  const int wm = (wave >> 1) * 64, wn = (wave & 1) * 64;

  f32x4 acc[4][4];
#pragma unroll
  for (int a = 0; a < 4; ++a)
#pragma unroll
    for (int bq = 0; bq < 4; ++bq) acc[a][bq] = (f32x4){0.f, 0.f, 0.f, 0.f};

  for (int k0 = 0; k0 < Kd; k0 += 32) {
#pragma unroll
    for (int it = 0; it < 2; ++it) {
      int cch = tid + 256 * it;
      int r = cch >> 2, cc = cch & 3;
      size_t ao = (size_t)(m0 + r) * Kd + k0 + cc * 8;
      size_t bo = (size_t)(n0 + r) * Kd + k0 + cc * 8;
      *(i32x4*)&AshH[r][cc * 8] = *(const i32x4*)(Ah + ao);
      *(i32x4*)&AshL[r][cc * 8] = *(const i32x4*)(Al + ao);
      *(i32x4*)&BshH[r][cc * 8] = *(const i32x4*)(Bzh + bo);
      *(i32x4*)&BshL[r][cc * 8] = *(const i32x4*)(Bzl + bo);
    }
    __syncthreads();
    short8 afh[4], afl[4], bfh[4], bfl[4];
#pragma unroll
    for (int mt = 0; mt < 4; ++mt) {
      afh[mt] = *(const short8*)&AshH[wm + mt * 16 + lr][g * 8];
      afl[mt] = *(const short8*)&AshL[wm + mt * 16 + lr][g * 8];
    }
#pragma unroll
    for (int nt = 0; nt < 4; ++nt) {
      bfh[nt] = *(const short8*)&BshH[wn + nt * 16 + lr][g * 8];
      bfl[nt] = *(const short8*)&BshL[wn + nt * 16 + lr][g * 8];
    }
#pragma unroll
    for (int mt = 0; mt < 4; ++mt)
#pragma unroll
      for (int nt = 0; nt < 4; ++nt) {
        f32x4 a = acc[mt][nt];
        a = __builtin_amdgcn_mfma_f32_16x16x32_bf16(afl[mt], bfh[nt], a, 0, 0, 0);
        a = __builtin_amdgcn_mfma_f32_16x16x32_bf16(afh[mt], bfl[nt], a, 0, 0, 0);
        a = __builtin_amdgcn_mfma_f32_16x16x32_bf16(afh[mt], bfh[nt], a, 0, 0, 0);
        acc[mt][nt] = a;
      }
    __syncthreads();
  }
#pragma unroll
  for (int mt = 0; mt < 4; ++mt)
#pragma unroll
    for (int nt = 0; nt < 4; ++nt)
#pragma unroll
      for (int r = 0; r < 4; ++r) {
        int m = m0 + wm + mt * 16 + g * 4 + r;
        int n = n0 + wn + nt * 16 + lr;
        Cz[(size_t)m * Nd + n] = acc[mt][nt][r];
      }
}

// ---------------- recurrent scan: 1 block (512 thr) per (b,n) chain ----------------
// r8-verified numerics; r9 deltas:
//   (1) one chain per block again (32 blocks x 512).
//   (2) ping-pong Hh/Hl planes -> ONE barrier per step. Window audit: reads of
//       plane p (B-frags, step t) and writes of plane p (step t+1) are separated
//       by step t's barrier; ypart is parity-double-buffered the same way.
//   (3) y computed in-register from exact f32 H_{t+1}: per lane q[kq]*H -> 4-stage
//       shfl_xor reduce over lr; lr==0 lanes write ypart[par][wk][w]; post-barrier
//       waves wk==0 (lanes<32) finalize 4 partials and store y directly to global.
//       Ht packed copy deleted.
// Row planes: row k at byte k*128, elem v at byte (2v) ^ ((k&7)<<4)  [verified].
__global__ __launch_bounds__(512) void scan_kernel(
    const float* __restrict__ qbuf, const float* __restrict__ kbuf,
    const float* __restrict__ vbuf, const float* __restrict__ fbuf,
    const float* __restrict__ W, unsigned short* __restrict__ yb,
    float* __restrict__ Hout) {
  const int tid = threadIdx.x;
  const int wave = tid >> 6, lane = tid & 63;
  const int g = lane >> 4, lr = lane & 15;
  const int wk = wave & 3, wh = wave >> 2;
  const int b = blockIdx.x >> 3, n = blockIdx.x & 7;
  const int kq = wk * 16 + lr;
  const int swz = (kq & 7) << 4;

  __shared__ unsigned short Hh[2][4096];   // 2 x 8 KB hi plane (ping-pong)
  __shared__ unsigned short Hl[2][4096];   // 2 x 8 KB lo plane
  __shared__ float stage[2][16][192];      // 24 KB
  __shared__ float fs[2][16];
  __shared__ float ypart[2][4][64];        // 2 KB, parity ping-pong

  // zero plane 0 (H_0 = 0)
  for (int i = tid; i < 2048; i += 512) {
    ((unsigned int*)Hh[0])[i] = 0u;
    ((unsigned int*)Hl[0])[i] = 0u;
  }

  // W^T split hi/lo fragments (RNE hi) -- verified verbatim
  const float* Wn = W + (size_t)n * 4096;
  short8 Af[2][2], Alw[2][2];
#pragma unroll
  for (int u = 0; u < 2; ++u)
#pragma unroll
    for (int s = 0; s < 2; ++s) {
      int wcol = (wh * 2 + u) * 16 + lr;
      short8 ah, al;
#pragma unroll
      for (int j = 0; j < 8; ++j) {
        float wv = Wn[(size_t)(s * 32 + g * 8 + j) * 64 + wcol];
        unsigned short hb = f2bf(wv);
        ah[j] = (short)hb;
        al[j] = (short)f2bf(wv - bf2f(hb));
      }
      Af[u][s] = ah; Alw[u][s] = al;
    }

  // chunk staging: 16 steps x 192 floats = 768 f32x4
  auto stage_chunk = [&](int c, int buf) {
#pragma unroll
    for (int i = 0; i < 2; ++i) {
      int fi = tid + i * 512;
      if (fi < 768) {
        int st = fi / 48, un = fi - st * 48;
        const float* basep = (un < 16) ? qbuf : (un < 32) ? kbuf : vbuf;
        f32x4 val = *(const f32x4*)(basep + (size_t)(b * 1024 + c * 16 + st) * 512 +
                                    n * 64 + (un & 15) * 4);
        *(f32x4*)&stage[buf][st][un * 4] = val;
      }
    }
    if (tid < 16) fs[buf][tid] = fbuf[(size_t)(b * 1024 + c * 16 + tid) * 8 + n];
  };

  f32x4 HA = (f32x4){0.f, 0.f, 0.f, 0.f};   // H[kq][(2wh+0)*16+4g+r], f32 master
  f32x4 HB = (f32x4){0.f, 0.f, 0.f, 0.f};   // H[kq][(2wh+1)*16+4g+r]
  int sb = 0, pp = 0;

  stage_chunk(0, 0);
  __syncthreads();

  const f32x4 zf = (f32x4){0.f, 0.f, 0.f, 0.f};
  const int bo0 = (16 * g) ^ swz;
  const int bo1 = (64 + 16 * g) ^ swz;
  const int wo0 = ((2 * wh + 0) * 32 + 8 * g) ^ swz;
  const int wo1 = ((2 * wh + 1) * 32 + 8 * g) ^ swz;
  const float K2L2E = 2.885390081777927f;   // 2*log2(e)
  unsigned short* ybase = yb + (size_t)b * 1024 * 512 + n * 64;

  for (int c = 0; c < 64; ++c) {
    if (c < 63) stage_chunk(c + 1, sb ^ 1);
    for (int tl = 0; tl < 16; ++tl) {
      const int t = c * 16 + tl;
      const int yp = t & 1;
      const float* srow = &stage[sb][tl][0];

      // B-frags of H_t from plane pp
      const char* hrh = (const char*)(Hh[pp] + kq * 64);
      const char* hrl = (const char*)(Hl[pp] + kq * 64);
      short8 Bh0 = *(const short8*)(hrh + bo0);
      short8 Bh1 = *(const short8*)(hrh + bo1);
      short8 Bl0 = *(const short8*)(hrl + bo0);
      short8 Bl1 = *(const short8*)(hrl + bo1);

      // 12 MFMAs: 3-term split, 4 independent chains of 3 (short critical path)
      f32x4 cA0 = __builtin_amdgcn_mfma_f32_16x16x32_bf16(Alw[0][0], Bh0, zf, 0, 0, 0);
      f32x4 cB0 = __builtin_amdgcn_mfma_f32_16x16x32_bf16(Alw[0][1], Bh1, zf, 0, 0, 0);
      f32x4 cA1 = __builtin_amdgcn_mfma_f32_16x16x32_bf16(Alw[1][0], Bh0, zf, 0, 0, 0);
      f32x4 cB1 = __builtin_amdgcn_mfma_f32_16x16x32_bf16(Alw[1][1], Bh1, zf, 0, 0, 0);
      cA0 = __builtin_amdgcn_mfma_f32_16x16x32_bf16(Af[0][1], Bh1, cA0, 0, 0, 0);
      cB0 = __builtin_amdgcn_mfma_f32_16x16x32_bf16(Af[0][1], Bl1, cB0, 0, 0, 0);
      cA1 = __builtin_amdgcn_mfma_f32_16x16x32_bf16(Af[1][1], Bh1, cA1, 0, 0, 0);
      cB1 = __builtin_amdgcn_mfma_f32_16x16x32_bf16(Af[1][1], Bl1, cB1, 0, 0, 0);
      cA0 = __builtin_amdgcn_mfma_f32_16x16x32_bf16(Af[0][0], Bh0, cA0, 0, 0, 0);
      cB0 = __builtin_amdgcn_mfma_f32_16x16x32_bf16(Af[0][0], Bl0, cB0, 0, 0, 0);
      cA1 = __builtin_amdgcn_mfma_f32_16x16x32_bf16(Af[1][0], Bh0, cA1, 0, 0, 0);
      cB1 = __builtin_amdgcn_mfma_f32_16x16x32_bf16(Af[1][0], Bl0, cB1, 0, 0, 0);

      float kval = srow[64 + kq];
      f32x4 vv0 = *(const f32x4*)(srow + 128 + (2 * wh + 0) * 16 + 4 * g);
      f32x4 vv1 = *(const f32x4*)(srow + 128 + (2 * wh + 1) * 16 + 4 * g);
      float fc = fs[sb][tl];

      f32x4 a0 = cA0 + cB0;
      f32x4 a1 = cA1 + cB1;

      // tanh (exp2-fused, overflow-safe) + gate blend -> H_{t+1} (f32, exact)
#pragma unroll
      for (int r = 0; r < 4; ++r) {
        float arg0 = fmaf(kval, vv0[r], a0[r]);
        float c0 = fmaf(-2.f, __builtin_amdgcn_rcpf(1.f + __builtin_amdgcn_exp2f(arg0 * K2L2E)), 1.f);
        HA[r] = fmaf(fc, HA[r] - c0, c0);
        float arg1 = fmaf(kval, vv1[r], a1[r]);
        float c1 = fmaf(-2.f, __builtin_amdgcn_rcpf(1.f + __builtin_amdgcn_exp2f(arg1 * K2L2E)), 1.f);
        HB[r] = fmaf(fc, HB[r] - c1, c1);
      }

      // y-reduce in-register: partial_w = sum_{k in wave} q[k]*H_{t+1}[k][w]
      {
        float qs = srow[kq];
        float yv0 = qs * HA[0], yv1 = qs * HA[1], yv2 = qs * HA[2], yv3 = qs * HA[3];
        float yv4 = qs * HB[0], yv5 = qs * HB[1], yv6 = qs * HB[2], yv7 = qs * HB[3];
#pragma unroll
        for (int m = 1; m < 16; m <<= 1) {
          yv0 += __shfl_xor(yv0, m, 64);
          yv1 += __shfl_xor(yv1, m, 64);
          yv2 += __shfl_xor(yv2, m, 64);
          yv3 += __shfl_xor(yv3, m, 64);
          yv4 += __shfl_xor(yv4, m, 64);
          yv5 += __shfl_xor(yv5, m, 64);
          yv6 += __shfl_xor(yv6, m, 64);
          yv7 += __shfl_xor(yv7, m, 64);
        }
        if (lr == 0) {
          float* yp0 = &ypart[yp][wk][wh * 32 + 4 * g];
          yp0[0] = yv0; yp0[1] = yv1; yp0[2] = yv2; yp0[3] = yv3;
          float* yp1 = &ypart[yp][wk][wh * 32 + 16 + 4 * g];
          yp1[0] = yv4; yp1[1] = yv5; yp1[2] = yv6; yp1[3] = yv7;
        }
      }

      // pack (cvt_pk) and write H_{t+1} to plane pp^1
      {
        char* hwh = (char*)(Hh[pp ^ 1] + kq * 64);
        char* hwl = (char*)(Hl[pp ^ 1] + kq * 64);
        unsigned ph0 = cvt_pk_bf16(HA[0], HA[1]);
        unsigned ph1 = cvt_pk_bf16(HA[2], HA[3]);
        float r0 = HA[0] - __builtin_bit_cast(float, ph0 << 16);
        float r1 = HA[1] - __builtin_bit_cast(float, ph0 & 0xFFFF0000u);
        float r2 = HA[2] - __builtin_bit_cast(float, ph1 << 16);
        float r3 = HA[3] - __builtin_bit_cast(float, ph1 & 0xFFFF0000u);
        *(u32x2*)(hwh + wo0) = (u32x2){ph0, ph1};
        *(u32x2*)(hwl + wo0) = (u32x2){cvt_pk_bf16(r0, r1), cvt_pk_bf16(r2, r3)};
        unsigned qh0 = cvt_pk_bf16(HB[0], HB[1]);
        unsigned qh1 = cvt_pk_bf16(HB[2], HB[3]);
        float s0 = HB[0] - __builtin_bit_cast(float, qh0 << 16);
        float s1 = HB[1] - __builtin_bit_cast(float, qh0 & 0xFFFF0000u);
        float s2 = HB[2] - __builtin_bit_cast(float, qh1 << 16);
        float s3 = HB[3] - __builtin_bit_cast(float, qh1 & 0xFFFF0000u);
        *(u32x2*)(hwh + wo1) = (u32x2){qh0, qh1};
        *(u32x2*)(hwl + wo1) = (u32x2){cvt_pk_bf16(s0, s1), cvt_pk_bf16(s2, s3)};
      }

      __syncthreads();   // single barrier: plane pp^1 + ypart[yp] visible

      // finalize y_t: only waves wk==0 (waves 0 and 4), lanes 0..31
      if (wk == 0 && lane < 32) {
        int w = wh * 32 + lane;
        float ysum = ypart[yp][0][w] + ypart[yp][1][w] +
                     ypart[yp][2][w] + ypart[yp][3][w];
        ybase[(size_t)t * 512 + w] = f2bf(ysum);
      }
      pp ^= 1;
    }
    sb ^= 1;
  }

  // H_final (f32 master)
  float* Ho = Hout + (size_t)(b * 8 + n) * 4096;
  *(f32x4*)&Ho[(size_t)kq * 64 + (wh * 2 + 0) * 16 + g * 4] = HA;
  *(f32x4*)&Ho[(size_t)kq * 64 + (wh * 2 + 1) * 16 + g * 4] = HB;
}

// ---------------- launch ----------------
extern "C" void kernel_launch(void* const* d_in, const int* in_sizes, int n_in,
                              void* d_out, int out_size, void* d_ws, size_t ws_size,
                              hipStream_t stream) {
  const float* x   = (const float*)d_in[0];
  const float* Wq  = (const float*)d_in[1];
  const float* Wk  = (const float*)d_in[2];
  const float* Wv  = (const float*)d_in[3];
  const float* Wf  = (const float*)d_in[4];
  const float* bfv = (const float*)d_in[5];
  const float* cwq = (const float*)d_in[6];
  const float* cwk = (const float*)d_in[7];
  const float* cwv = (const float*)d_in[8];
  const float* W   = (const float*)d_in[9];
  const float* Wo  = (const float*)d_in[10];
  float* outp = (float*)d_out;

  char* ws = (char*)d_ws;
  size_t off = 0;
  auto alloc = [&](size_t bytes) {
    char* pp = ws + off;
    off = (off + bytes + 255) & ~(size_t)255;
    return pp;
  };
  unsigned short* xbh  = (unsigned short*)alloc((size_t)4194304 * 2);
  unsigned short* xbl  = (unsigned short*)alloc((size_t)4194304 * 2);
  unsigned short* wtbh = (unsigned short*)alloc((size_t)3 * 524288 * 2);
  unsigned short* wtbl = (unsigned short*)alloc((size_t)3 * 524288 * 2);
  float* pre  = (float*)alloc((size_t)3 * 2097152 * 4);
  float* qkv  = (float*)alloc((size_t)3 * 2097152 * 4);
  float* fbuf = (float*)alloc((size_t)32768 * 4);
  unsigned short* yb  = (unsigned short*)alloc((size_t)2097152 * 2);
  unsigned short* wot = (unsigned short*)alloc((size_t)524288 * 2);

  // casts / transposes (split hi/lo for the amplified paths)
  cast_split_kernel<<<4096, 256, 0, stream>>>(x, xbh, xbl, 1048576);
  tcast_split_kernel<<<2048, 256, 0, stream>>>(Wq, wtbh, wtbl, 1024, 512);
  tcast_split_kernel<<<2048, 256, 0, stream>>>(Wk, wtbh + 524288, wtbl + 524288, 1024, 512);
  tcast_split_kernel<<<2048, 256, 0, stream>>>(Wv, wtbh + 2 * 524288, wtbl + 2 * 524288, 1024, 512);
  // gate
  fgate_kernel<<<1024, 256, 0, stream>>>(x, Wf, bfv, fbuf);
  // q pre-activation: plain bf16 (un-amplified path)
  dim3 gq(32, 4, 1);
  gemm_bf16_kernel<<<gq, 256, 0, stream>>>(xbh, wtbh, pre, 1024, 512,
                                           (size_t)0, (size_t)0);
  // k,v pre-activations: split-bf16 (amplified path)
  dim3 gkv(32, 4, 2);
  gemm_split_kernel<<<gkv, 256, 0, stream>>>(xbh, xbl, wtbh + 524288, wtbl + 524288,
                                             pre + 2097152, 1024, 512,
                                             (size_t)524288, (size_t)2097152);
  // conv + silu (all three in one launch)
  dim3 gc(8192, 3, 1);
  conv_silu_kernel<<<gc, 256, 0, stream>>>(pre, cwq, cwk, cwv, qkv);
  // recurrent scan: 32 blocks x 512 threads, one chain per block
  scan_kernel<<<32, 512, 0, stream>>>(qkv, qkv + 2097152, qkv + 2 * 2097152, fbuf, W,
                                      yb, outp + 4194304);
  // output projection
  tcast_kernel<<<2048, 256, 0, stream>>>(Wo, wot, 512, 1024);
  dim3 g2(32, 8, 1);
  gemm_bf16_kernel<<<g2, 256, 0, stream>>>(yb, wot, outp, 512, 1024, (size_t)0, (size_t)0);
}

// Round 10
// 1208.853 us; speedup vs baseline: 1.6973x; 1.3165x over previous
//
#include <hip/hip_runtime.h>
#include <hip/hip_bf16.h>

typedef __attribute__((ext_vector_type(4))) float f32x4;
typedef __attribute__((ext_vector_type(8))) short short8;
typedef __attribute__((ext_vector_type(4))) int i32x4;
typedef __attribute__((ext_vector_type(2))) unsigned int u32x2;
typedef __attribute__((ext_vector_type(4))) unsigned short u16x4;

static __device__ __forceinline__ unsigned short f2bf(float f) {
  unsigned u = __builtin_bit_cast(unsigned, f);
  u = u + 0x7FFFu + ((u >> 16) & 1u);   // RNE
  return (unsigned short)(u >> 16);
}
static __device__ __forceinline__ float bf2f(unsigned short b) {
  unsigned u = ((unsigned)b) << 16;
  return __builtin_bit_cast(float, u);
}
static __device__ __forceinline__ float sigmoidf_fast(float x) {
  return __builtin_amdgcn_rcpf(1.f + __expf(-x));
}
// packed bf16 pair: low16 = bf16(a), high16 = bf16(b)
static __device__ __forceinline__ unsigned cvt_pk_bf16(float a, float b) {
  unsigned d;
  asm volatile("v_cvt_pk_bf16_f32 %0, %1, %2" : "=v"(d) : "v"(a), "v"(b));
  return d;
}
// Row-wise (16-lane DPP row) inclusive sum; total lands in lane (lane&15)==15.
// VALU-only: no DS-pipe traffic (vs ds_bpermute shuffles).
static __device__ __forceinline__ float row_sum16(float v) {
  int x;
  x = __builtin_amdgcn_update_dpp(0, __builtin_bit_cast(int, v), 0x111, 0xF, 0xF, true);
  v += __builtin_bit_cast(float, x);   // row_shr:1
  x = __builtin_amdgcn_update_dpp(0, __builtin_bit_cast(int, v), 0x112, 0xF, 0xF, true);
  v += __builtin_bit_cast(float, x);   // row_shr:2
  x = __builtin_amdgcn_update_dpp(0, __builtin_bit_cast(int, v), 0x114, 0xF, 0xF, true);
  v += __builtin_bit_cast(float, x);   // row_shr:4
  x = __builtin_amdgcn_update_dpp(0, __builtin_bit_cast(int, v), 0x118, 0xF, 0xF, true);
  v += __builtin_bit_cast(float, x);   // row_shr:8
  return v;
}

// ---------------- cast f32 -> hi/lo bf16 pair (RNE hi) ----------------
__global__ void cast_split_kernel(const float* __restrict__ in,
                                  unsigned short* __restrict__ oh,
                                  unsigned short* __restrict__ ol, int n4) {
  int i = blockIdx.x * blockDim.x + threadIdx.x;
  if (i >= n4) return;
  f32x4 v = ((const f32x4*)in)[i];
  u16x4 h, l;
#pragma unroll
  for (int j = 0; j < 4; ++j) {
    unsigned short hb = f2bf(v[j]);
    h[j] = hb;
    l[j] = f2bf(v[j] - bf2f(hb));
  }
  ((u16x4*)oh)[i] = h;
  ((u16x4*)ol)[i] = l;
}

// ---------------- transpose + cast: (R,C) f32 -> (C,R) bf16 ----------------
__global__ void tcast_kernel(const float* __restrict__ in,
                             unsigned short* __restrict__ out, int R, int C) {
  int i = blockIdx.x * blockDim.x + threadIdx.x;
  if (i >= R * C) return;
  int r = i / C, c = i % C;
  out[(size_t)c * R + r] = f2bf(in[i]);
}

// ---------------- transpose + split cast: (R,C) f32 -> (C,R) hi/lo bf16 ----------------
__global__ void tcast_split_kernel(const float* __restrict__ in,
                                   unsigned short* __restrict__ oh,
                                   unsigned short* __restrict__ ol, int R, int C) {
  int i = blockIdx.x * blockDim.x + threadIdx.x;
  if (i >= R * C) return;
  int r = i / C, c = i % C;
  float v = in[i];
  unsigned short hb = f2bf(v);
  oh[(size_t)c * R + r] = hb;
  ol[(size_t)c * R + r] = f2bf(v - bf2f(hb));
}

// ---------------- f gate: one wave per token row (pure f32) ----------------
__global__ __launch_bounds__(256) void fgate_kernel(const float* __restrict__ x,
                                                    const float* __restrict__ Wf,
                                                    const float* __restrict__ bfv,
                                                    float* __restrict__ fbuf) {
  int wid = (blockIdx.x * blockDim.x + threadIdx.x) >> 6;  // token row 0..4095
  int lane = threadIdx.x & 63;
  const float* xr = x + (size_t)wid * 1024;
  float acc[8] = {0.f, 0.f, 0.f, 0.f, 0.f, 0.f, 0.f, 0.f};
#pragma unroll 4
  for (int it = 0; it < 16; ++it) {
    int d = it * 64 + lane;
    float xv = xr[d];
    f32x4 w0 = *(const f32x4*)(Wf + (size_t)d * 8);
    f32x4 w1 = *(const f32x4*)(Wf + (size_t)d * 8 + 4);
    acc[0] += xv * w0[0]; acc[1] += xv * w0[1];
    acc[2] += xv * w0[2]; acc[3] += xv * w0[3];
    acc[4] += xv * w1[0]; acc[5] += xv * w1[1];
    acc[6] += xv * w1[2]; acc[7] += xv * w1[3];
  }
#pragma unroll
  for (int n = 0; n < 8; ++n) {
#pragma unroll
    for (int m = 1; m < 64; m <<= 1) acc[n] += __shfl_xor(acc[n], m, 64);
  }
  if (lane == 0) {
#pragma unroll
    for (int n = 0; n < 8; ++n)
      fbuf[(size_t)wid * 8 + n] = sigmoidf_fast(acc[n] + bfv[n]);
  }
}

// ---------------- causal depthwise conv (KC=4) + SiLU, all 3 tensors ----------------
__global__ void conv_silu_kernel(const float* __restrict__ pre,
                                 const float* __restrict__ cwq,
                                 const float* __restrict__ cwk,
                                 const float* __restrict__ cwv,
                                 float* __restrict__ outb) {
  int i = blockIdx.x * blockDim.x + threadIdx.x;  // B*L*512
  int which = blockIdx.y;
  const float* cw = (which == 0) ? cwq : (which == 1) ? cwk : cwv;
  const float* p = pre + (size_t)which * 2097152 + i;
  int c = i & 511;
  int l = (i >> 9) & 1023;
  float w0 = cw[c * 4 + 0], w1 = cw[c * 4 + 1], w2 = cw[c * 4 + 2], w3 = cw[c * 4 + 3];
  float acc = w3 * p[0];
  if (l >= 1) acc += w2 * p[-512];
  if (l >= 2) acc += w1 * p[-1024];
  if (l >= 3) acc += w0 * p[-1536];
  outb[(size_t)which * 2097152 + i] = acc * sigmoidf_fast(acc);
}

// ---------------- plain bf16 MFMA GEMM: C(M,Nd) = A * Bt^T ----------------
__global__ __launch_bounds__(256) void gemm_bf16_kernel(
    const unsigned short* __restrict__ A, const unsigned short* __restrict__ Bt,
    float* __restrict__ C, int Kd, int Nd, size_t BtStride, size_t CStride) {
  __shared__ unsigned short Ash[128][40];
  __shared__ unsigned short Bsh[128][40];
  const int tid = threadIdx.x;
  const int wave = tid >> 6, lane = tid & 63;
  const int g = lane >> 4, lr = lane & 15;
  const int m0 = blockIdx.x * 128, n0 = blockIdx.y * 128;
  const unsigned short* Bz = Bt + blockIdx.z * BtStride;
  float* Cz = C + blockIdx.z * CStride;
  const int wm = (wave >> 1) * 64, wn = (wave & 1) * 64;

  f32x4 acc[4][4];
#pragma unroll
  for (int a = 0; a < 4; ++a)
#pragma unroll
    for (int bq = 0; bq < 4; ++bq) acc[a][bq] = (f32x4){0.f, 0.f, 0.f, 0.f};

  for (int k0 = 0; k0 < Kd; k0 += 32) {
#pragma unroll
    for (int it = 0; it < 2; ++it) {
      int cch = tid + 256 * it;
      int r = cch >> 2, cc = cch & 3;
      *(i32x4*)&Ash[r][cc * 8] = *(const i32x4*)(A + (size_t)(m0 + r) * Kd + k0 + cc * 8);
      *(i32x4*)&Bsh[r][cc * 8] = *(const i32x4*)(Bz + (size_t)(n0 + r) * Kd + k0 + cc * 8);
    }
    __syncthreads();
    short8 af[4], bfr[4];
#pragma unroll
    for (int mt = 0; mt < 4; ++mt) af[mt] = *(const short8*)&Ash[wm + mt * 16 + lr][g * 8];
#pragma unroll
    for (int nt = 0; nt < 4; ++nt) bfr[nt] = *(const short8*)&Bsh[wn + nt * 16 + lr][g * 8];
#pragma unroll
    for (int mt = 0; mt < 4; ++mt)
#pragma unroll
      for (int nt = 0; nt < 4; ++nt)
        acc[mt][nt] = __builtin_amdgcn_mfma_f32_16x16x32_bf16(af[mt], bfr[nt], acc[mt][nt], 0, 0, 0);
    __syncthreads();
  }
#pragma unroll
  for (int mt = 0; mt < 4; ++mt)
#pragma unroll
    for (int nt = 0; nt < 4; ++nt)
#pragma unroll
      for (int r = 0; r < 4; ++r) {
        int m = m0 + wm + mt * 16 + g * 4 + r;
        int n = n0 + wn + nt * 16 + lr;
        Cz[(size_t)m * Nd + n] = acc[mt][nt][r];
      }
}

// ---------------- split-bf16 (3-term f32-emulation) GEMM ----------------
__global__ __launch_bounds__(256) void gemm_split_kernel(
    const unsigned short* __restrict__ Ah, const unsigned short* __restrict__ Al,
    const unsigned short* __restrict__ Bth, const unsigned short* __restrict__ Btl,
    float* __restrict__ C, int Kd, int Nd, size_t BtStride, size_t CStride) {
  __shared__ unsigned short AshH[128][40];
  __shared__ unsigned short AshL[128][40];
  __shared__ unsigned short BshH[128][40];
  __shared__ unsigned short BshL[128][40];
  const int tid = threadIdx.x;
  const int wave = tid >> 6, lane = tid & 63;
  const int g = lane >> 4, lr = lane & 15;
  const int m0 = blockIdx.x * 128, n0 = blockIdx.y * 128;
  const unsigned short* Bzh = Bth + blockIdx.z * BtStride;
  const unsigned short* Bzl = Btl + blockIdx.z * BtStride;
  float* Cz = C + blockIdx.z * CStride;
  const int wm = (wave >> 1) * 64, wn = (wave & 1) * 64;

  f32x4 acc[4][4];
#pragma unroll
  for (int a = 0; a < 4; ++a)
#pragma unroll
    for (int bq = 0; bq < 4; ++bq) acc[a][bq] = (f32x4){0.f, 0.f, 0.f, 0.f};

  for (int k0 = 0; k0 < Kd; k0 += 32) {
#pragma unroll
    for (int it = 0; it < 2; ++it) {
      int cch = tid + 256 * it;
      int r = cch >> 2, cc = cch & 3;
      size_t ao = (size_t)(m0 + r) * Kd + k0 + cc * 8;
      size_t bo = (size_t)(n0 + r) * Kd + k0 + cc * 8;
      *(i32x4*)&AshH[r][cc * 8] = *(const i32x4*)(Ah + ao);
      *(i32x4*)&AshL[r][cc * 8] = *(const i32x4*)(Al + ao);
      *(i32x4*)&BshH[r][cc * 8] = *(const i32x4*)(Bzh + bo);
      *(i32x4*)&BshL[r][cc * 8] = *(const i32x4*)(Bzl + bo);
    }
    __syncthreads();
    short8 afh[4], afl[4], bfh[4], bfl[4];
#pragma unroll
    for (int mt = 0; mt < 4; ++mt) {
      afh[mt] = *(const short8*)&AshH[wm + mt * 16 + lr][g * 8];
      afl[mt] = *(const short8*)&AshL[wm + mt * 16 + lr][g * 8];
    }
#pragma unroll
    for (int nt = 0; nt < 4; ++nt) {
      bfh[nt] = *(const short8*)&BshH[wn + nt * 16 + lr][g * 8];
      bfl[nt] = *(const short8*)&BshL[wn + nt * 16 + lr][g * 8];
    }
#pragma unroll
    for (int mt = 0; mt < 4; ++mt)
#pragma unroll
      for (int nt = 0; nt < 4; ++nt) {
        f32x4 a = acc[mt][nt];
        a = __builtin_amdgcn_mfma_f32_16x16x32_bf16(afl[mt], bfh[nt], a, 0, 0, 0);
        a = __builtin_amdgcn_mfma_f32_16x16x32_bf16(afh[mt], bfl[nt], a, 0, 0, 0);
        a = __builtin_amdgcn_mfma_f32_16x16x32_bf16(afh[mt], bfh[nt], a, 0, 0, 0);
        acc[mt][nt] = a;
      }
    __syncthreads();
  }
#pragma unroll
  for (int mt = 0; mt < 4; ++mt)
#pragma unroll
    for (int nt = 0; nt < 4; ++nt)
#pragma unroll
      for (int r = 0; r < 4; ++r) {
        int m = m0 + wm + mt * 16 + g * 4 + r;
        int n = n0 + wn + nt * 16 + lr;
        Cz[(size_t)m * Nd + n] = acc[mt][nt][r];
      }
}

// ---------------- recurrent scan: 1 block (512 thr) per (b,n) chain ----------------
// r9-verified skeleton (ping-pong planes, 1 barrier/step, in-register y).
// r10 deltas:
//   (1) y-reduce via DPP row_shr (VALU pipe) instead of 32 ds_bpermute shuffles
//       (DS pipe was saturated: ~1540 of ~2500 cyc/step). Sum lands at lr==15.
//   (2) y buffered in LDS (yst), flushed to global once per 16-step chunk
//       (removes per-step global-store vmcnt drain at the barrier).
// Row planes: row k at byte k*128, elem v at byte (2v) ^ ((k&7)<<4)  [verified].
__global__ __launch_bounds__(512) void scan_kernel(
    const float* __restrict__ qbuf, const float* __restrict__ kbuf,
    const float* __restrict__ vbuf, const float* __restrict__ fbuf,
    const float* __restrict__ W, unsigned short* __restrict__ yb,
    float* __restrict__ Hout) {
  const int tid = threadIdx.x;
  const int wave = tid >> 6, lane = tid & 63;
  const int g = lane >> 4, lr = lane & 15;
  const int wk = wave & 3, wh = wave >> 2;
  const int b = blockIdx.x >> 3, n = blockIdx.x & 7;
  const int kq = wk * 16 + lr;
  const int swz = (kq & 7) << 4;

  __shared__ unsigned short Hh[2][4096];   // 2 x 8 KB hi plane (ping-pong)
  __shared__ unsigned short Hl[2][4096];   // 2 x 8 KB lo plane
  __shared__ float stage[2][16][192];      // 24 KB
  __shared__ float fs[2][16];
  __shared__ float ypart[2][4][64];        // 2 KB, parity ping-pong
  __shared__ unsigned short yst[16 * 64];  // 2 KB y chunk buffer

  // zero plane 0 (H_0 = 0)
  for (int i = tid; i < 2048; i += 512) {
    ((unsigned int*)Hh[0])[i] = 0u;
    ((unsigned int*)Hl[0])[i] = 0u;
  }

  // W^T split hi/lo fragments (RNE hi) -- verified verbatim
  const float* Wn = W + (size_t)n * 4096;
  short8 Af[2][2], Alw[2][2];
#pragma unroll
  for (int u = 0; u < 2; ++u)
#pragma unroll
    for (int s = 0; s < 2; ++s) {
      int wcol = (wh * 2 + u) * 16 + lr;
      short8 ah, al;
#pragma unroll
      for (int j = 0; j < 8; ++j) {
        float wv = Wn[(size_t)(s * 32 + g * 8 + j) * 64 + wcol];
        unsigned short hb = f2bf(wv);
        ah[j] = (short)hb;
        al[j] = (short)f2bf(wv - bf2f(hb));
      }
      Af[u][s] = ah; Alw[u][s] = al;
    }

  // chunk staging: 16 steps x 192 floats = 768 f32x4
  auto stage_chunk = [&](int c, int buf) {
#pragma unroll
    for (int i = 0; i < 2; ++i) {
      int fi = tid + i * 512;
      if (fi < 768) {
        int st = fi / 48, un = fi - st * 48;
        const float* basep = (un < 16) ? qbuf : (un < 32) ? kbuf : vbuf;
        f32x4 val = *(const f32x4*)(basep + (size_t)(b * 1024 + c * 16 + st) * 512 +
                                    n * 64 + (un & 15) * 4);
        *(f32x4*)&stage[buf][st][un * 4] = val;
      }
    }
    if (tid < 16) fs[buf][tid] = fbuf[(size_t)(b * 1024 + c * 16 + tid) * 8 + n];
  };

  f32x4 HA = (f32x4){0.f, 0.f, 0.f, 0.f};   // H[kq][(2wh+0)*16+4g+r], f32 master
  f32x4 HB = (f32x4){0.f, 0.f, 0.f, 0.f};   // H[kq][(2wh+1)*16+4g+r]
  int sb = 0, pp = 0;

  stage_chunk(0, 0);
  __syncthreads();

  const f32x4 zf = (f32x4){0.f, 0.f, 0.f, 0.f};
  const int bo0 = (16 * g) ^ swz;
  const int bo1 = (64 + 16 * g) ^ swz;
  const int wo0 = ((2 * wh + 0) * 32 + 8 * g) ^ swz;
  const int wo1 = ((2 * wh + 1) * 32 + 8 * g) ^ swz;
  const float K2L2E = 2.885390081777927f;   // 2*log2(e)

  for (int c = 0; c < 64; ++c) {
    if (c < 63) stage_chunk(c + 1, sb ^ 1);
    for (int tl = 0; tl < 16; ++tl) {
      const int t = c * 16 + tl;
      const int yp = t & 1;
      const float* srow = &stage[sb][tl][0];

      // B-frags of H_t from plane pp
      const char* hrh = (const char*)(Hh[pp] + kq * 64);
      const char* hrl = (const char*)(Hl[pp] + kq * 64);
      short8 Bh0 = *(const short8*)(hrh + bo0);
      short8 Bh1 = *(const short8*)(hrh + bo1);
      short8 Bl0 = *(const short8*)(hrl + bo0);
      short8 Bl1 = *(const short8*)(hrl + bo1);

      // 12 MFMAs: 3-term split, 4 independent chains of 3 (short critical path)
      f32x4 cA0 = __builtin_amdgcn_mfma_f32_16x16x32_bf16(Alw[0][0], Bh0, zf, 0, 0, 0);
      f32x4 cB0 = __builtin_amdgcn_mfma_f32_16x16x32_bf16(Alw[0][1], Bh1, zf, 0, 0, 0);
      f32x4 cA1 = __builtin_amdgcn_mfma_f32_16x16x32_bf16(Alw[1][0], Bh0, zf, 0, 0, 0);
      f32x4 cB1 = __builtin_amdgcn_mfma_f32_16x16x32_bf16(Alw[1][1], Bh1, zf, 0, 0, 0);
      cA0 = __builtin_amdgcn_mfma_f32_16x16x32_bf16(Af[0][1], Bh1, cA0, 0, 0, 0);
      cB0 = __builtin_amdgcn_mfma_f32_16x16x32_bf16(Af[0][1], Bl1, cB0, 0, 0, 0);
      cA1 = __builtin_amdgcn_mfma_f32_16x16x32_bf16(Af[1][1], Bh1, cA1, 0, 0, 0);
      cB1 = __builtin_amdgcn_mfma_f32_16x16x32_bf16(Af[1][1], Bl1, cB1, 0, 0, 0);
      cA0 = __builtin_amdgcn_mfma_f32_16x16x32_bf16(Af[0][0], Bh0, cA0, 0, 0, 0);
      cB0 = __builtin_amdgcn_mfma_f32_16x16x32_bf16(Af[0][0], Bl0, cB0, 0, 0, 0);
      cA1 = __builtin_amdgcn_mfma_f32_16x16x32_bf16(Af[1][0], Bh0, cA1, 0, 0, 0);
      cB1 = __builtin_amdgcn_mfma_f32_16x16x32_bf16(Af[1][0], Bl0, cB1, 0, 0, 0);

      float kval = srow[64 + kq];
      f32x4 vv0 = *(const f32x4*)(srow + 128 + (2 * wh + 0) * 16 + 4 * g);
      f32x4 vv1 = *(const f32x4*)(srow + 128 + (2 * wh + 1) * 16 + 4 * g);
      float fc = fs[sb][tl];

      f32x4 a0 = cA0 + cB0;
      f32x4 a1 = cA1 + cB1;

      // tanh (exp2-fused, overflow-safe) + gate blend -> H_{t+1} (f32, exact)
#pragma unroll
      for (int r = 0; r < 4; ++r) {
        float arg0 = fmaf(kval, vv0[r], a0[r]);
        float c0 = fmaf(-2.f, __builtin_amdgcn_rcpf(1.f + __builtin_amdgcn_exp2f(arg0 * K2L2E)), 1.f);
        HA[r] = fmaf(fc, HA[r] - c0, c0);
        float arg1 = fmaf(kval, vv1[r], a1[r]);
        float c1 = fmaf(-2.f, __builtin_amdgcn_rcpf(1.f + __builtin_amdgcn_exp2f(arg1 * K2L2E)), 1.f);
        HB[r] = fmaf(fc, HB[r] - c1, c1);
      }

      // y partials: sum over this wave's 16 k-lanes via DPP rows (VALU only).
      // Row sums land in lanes with lr==15 (one per g-row).
      {
        float qs = srow[kq];
        float yv0 = row_sum16(qs * HA[0]);
        float yv1 = row_sum16(qs * HA[1]);
        float yv2 = row_sum16(qs * HA[2]);
        float yv3 = row_sum16(qs * HA[3]);
        float yv4 = row_sum16(qs * HB[0]);
        float yv5 = row_sum16(qs * HB[1]);
        float yv6 = row_sum16(qs * HB[2]);
        float yv7 = row_sum16(qs * HB[3]);
        if (lr == 15) {
          *(f32x4*)&ypart[yp][wk][wh * 32 + 4 * g] = (f32x4){yv0, yv1, yv2, yv3};
          *(f32x4*)&ypart[yp][wk][wh * 32 + 16 + 4 * g] = (f32x4){yv4, yv5, yv6, yv7};
        }
      }

      // pack (cvt_pk) and write H_{t+1} to plane pp^1
      {
        char* hwh = (char*)(Hh[pp ^ 1] + kq * 64);
        char* hwl = (char*)(Hl[pp ^ 1] + kq * 64);
        unsigned ph0 = cvt_pk_bf16(HA[0], HA[1]);
        unsigned ph1 = cvt_pk_bf16(HA[2], HA[3]);
        float r0 = HA[0] - __builtin_bit_cast(float, ph0 << 16);
        float r1 = HA[1] - __builtin_bit_cast(float, ph0 & 0xFFFF0000u);
        float r2 = HA[2] - __builtin_bit_cast(float, ph1 << 16);
        float r3 = HA[3] - __builtin_bit_cast(float, ph1 & 0xFFFF0000u);
        *(u32x2*)(hwh + wo0) = (u32x2){ph0, ph1};
        *(u32x2*)(hwl + wo0) = (u32x2){cvt_pk_bf16(r0, r1), cvt_pk_bf16(r2, r3)};
        unsigned qh0 = cvt_pk_bf16(HB[0], HB[1]);
        unsigned qh1 = cvt_pk_bf16(HB[2], HB[3]);
        float s0 = HB[0] - __builtin_bit_cast(float, qh0 << 16);
        float s1 = HB[1] - __builtin_bit_cast(float, qh0 & 0xFFFF0000u);
        float s2 = HB[2] - __builtin_bit_cast(float, qh1 << 16);
        float s3 = HB[3] - __builtin_bit_cast(float, qh1 & 0xFFFF0000u);
        *(u32x2*)(hwh + wo1) = (u32x2){qh0, qh1};
        *(u32x2*)(hwl + wo1) = (u32x2){cvt_pk_bf16(s0, s1), cvt_pk_bf16(s2, s3)};
      }

      __syncthreads();   // single barrier: plane pp^1 + ypart[yp] visible

      // finalize y_t into yst: waves wk==0 (waves 0 and 4), lanes 0..31
      if (wk == 0 && lane < 32) {
        int w = wh * 32 + lane;
        float ysum = ypart[yp][0][w] + ypart[yp][1][w] +
                     ypart[yp][2][w] + ypart[yp][3][w];
        yst[tl * 64 + w] = f2bf(ysum);
      }
      pp ^= 1;
    }

    __syncthreads();  // yst complete for this chunk
    {  // flush y chunk: 512 threads x one u32 (2 bf16) coalesced
      int tl2 = tid >> 5, pv = (tid & 31) << 1;
      unsigned val = ((const unsigned*)yst)[tid];
      *(unsigned*)(yb + (size_t)(b * 1024 + c * 16 + tl2) * 512 + n * 64 + pv) = val;
    }
    sb ^= 1;
  }

  // H_final (f32 master)
  float* Ho = Hout + (size_t)(b * 8 + n) * 4096;
  *(f32x4*)&Ho[(size_t)kq * 64 + (wh * 2 + 0) * 16 + g * 4] = HA;
  *(f32x4*)&Ho[(size_t)kq * 64 + (wh * 2 + 1) * 16 + g * 4] = HB;
}

// ---------------- launch ----------------
extern "C" void kernel_launch(void* const* d_in, const int* in_sizes, int n_in,
                              void* d_out, int out_size, void* d_ws, size_t ws_size,
                              hipStream_t stream) {
  const float* x   = (const float*)d_in[0];
  const float* Wq  = (const float*)d_in[1];
  const float* Wk  = (const float*)d_in[2];
  const float* Wv  = (const float*)d_in[3];
  const float* Wf  = (const float*)d_in[4];
  const float* bfv = (const float*)d_in[5];
  const float* cwq = (const float*)d_in[6];
  const float* cwk = (const float*)d_in[7];
  const float* cwv = (const float*)d_in[8];
  const float* W   = (const float*)d_in[9];
  const float* Wo  = (const float*)d_in[10];
  float* outp = (float*)d_out;

  char* ws = (char*)d_ws;
  size_t off = 0;
  auto alloc = [&](size_t bytes) {
    char* pp = ws + off;
    off = (off + bytes + 255) & ~(size_t)255;
    return pp;
  };
  unsigned short* xbh  = (unsigned short*)alloc((size_t)4194304 * 2);
  unsigned short* xbl  = (unsigned short*)alloc((size_t)4194304 * 2);
  unsigned short* wtbh = (unsigned short*)alloc((size_t)3 * 524288 * 2);
  unsigned short* wtbl = (unsigned short*)alloc((size_t)3 * 524288 * 2);
  float* pre  = (float*)alloc((size_t)3 * 2097152 * 4);
  float* qkv  = (float*)alloc((size_t)3 * 2097152 * 4);
  float* fbuf = (float*)alloc((size_t)32768 * 4);
  unsigned short* yb  = (unsigned short*)alloc((size_t)2097152 * 2);
  unsigned short* wot = (unsigned short*)alloc((size_t)524288 * 2);

  // casts / transposes (split hi/lo for the amplified paths)
  cast_split_kernel<<<4096, 256, 0, stream>>>(x, xbh, xbl, 1048576);
  tcast_split_kernel<<<2048, 256, 0, stream>>>(Wq, wtbh, wtbl, 1024, 512);
  tcast_split_kernel<<<2048, 256, 0, stream>>>(Wk, wtbh + 524288, wtbl + 524288, 1024, 512);
  tcast_split_kernel<<<2048, 256, 0, stream>>>(Wv, wtbh + 2 * 524288, wtbl + 2 * 524288, 1024, 512);
  // gate
  fgate_kernel<<<1024, 256, 0, stream>>>(x, Wf, bfv, fbuf);
  // q pre-activation: plain bf16 (un-amplified path)
  dim3 gq(32, 4, 1);
  gemm_bf16_kernel<<<gq, 256, 0, stream>>>(xbh, wtbh, pre, 1024, 512,
                                           (size_t)0, (size_t)0);
  // k,v pre-activations: split-bf16 (amplified path)
  dim3 gkv(32, 4, 2);
  gemm_split_kernel<<<gkv, 256, 0, stream>>>(xbh, xbl, wtbh + 524288, wtbl + 524288,
                                             pre + 2097152, 1024, 512,
                                             (size_t)524288, (size_t)2097152);
  // conv + silu (all three in one launch)
  dim3 gc(8192, 3, 1);
  conv_silu_kernel<<<gc, 256, 0, stream>>>(pre, cwq, cwk, cwv, qkv);
  // recurrent scan: 32 blocks x 512 threads, one chain per block
  scan_kernel<<<32, 512, 0, stream>>>(qkv, qkv + 2097152, qkv + 2 * 2097152, fbuf, W,
                                      yb, outp + 4194304);
  // output projection
  tcast_kernel<<<2048, 256, 0, stream>>>(Wo, wot, 512, 1024);
  dim3 g2(32, 8, 1);
  gemm_bf16_kernel<<<g2, 256, 0, stream>>>(yb, wot, outp, 512, 1024, (size_t)0, (size_t)0);
}

// Round 11
// 721.435 us; speedup vs baseline: 2.8441x; 1.6756x over previous
//
#include <hip/hip_runtime.h>
#include <hip/hip_bf16.h>

typedef __attribute__((ext_vector_type(4))) float f32x4;
typedef __attribute__((ext_vector_type(8))) short short8;
typedef __attribute__((ext_vector_type(4))) int i32x4;
typedef __attribute__((ext_vector_type(2))) unsigned int u32x2;
typedef __attribute__((ext_vector_type(4))) unsigned short u16x4;

static __device__ __forceinline__ unsigned short f2bf(float f) {
  unsigned u = __builtin_bit_cast(unsigned, f);
  u = u + 0x7FFFu + ((u >> 16) & 1u);   // RNE
  return (unsigned short)(u >> 16);
}
static __device__ __forceinline__ float bf2f(unsigned short b) {
  unsigned u = ((unsigned)b) << 16;
  return __builtin_bit_cast(float, u);
}
static __device__ __forceinline__ float sigmoidf_fast(float x) {
  return __builtin_amdgcn_rcpf(1.f + __expf(-x));
}
// packed bf16 pair: low16 = bf16(a), high16 = bf16(b)
static __device__ __forceinline__ unsigned cvt_pk_bf16(float a, float b) {
  unsigned d;
  asm volatile("v_cvt_pk_bf16_f32 %0, %1, %2" : "=v"(d) : "v"(a), "v"(b));
  return d;
}
// Row-wise (16-lane DPP row) inclusive sum; total lands in lane (lane&15)==15.
static __device__ __forceinline__ float row_sum16(float v) {
  int x;
  x = __builtin_amdgcn_update_dpp(0, __builtin_bit_cast(int, v), 0x111, 0xF, 0xF, true);
  v += __builtin_bit_cast(float, x);   // row_shr:1
  x = __builtin_amdgcn_update_dpp(0, __builtin_bit_cast(int, v), 0x112, 0xF, 0xF, true);
  v += __builtin_bit_cast(float, x);   // row_shr:2
  x = __builtin_amdgcn_update_dpp(0, __builtin_bit_cast(int, v), 0x114, 0xF, 0xF, true);
  v += __builtin_bit_cast(float, x);   // row_shr:4
  x = __builtin_amdgcn_update_dpp(0, __builtin_bit_cast(int, v), 0x118, 0xF, 0xF, true);
  v += __builtin_bit_cast(float, x);   // row_shr:8
  return v;
}

// ---------------- cast f32 -> hi/lo bf16 pair (RNE hi) ----------------
__global__ void cast_split_kernel(const float* __restrict__ in,
                                  unsigned short* __restrict__ oh,
                                  unsigned short* __restrict__ ol, int n4) {
  int i = blockIdx.x * blockDim.x + threadIdx.x;
  if (i >= n4) return;
  f32x4 v = ((const f32x4*)in)[i];
  u16x4 h, l;
#pragma unroll
  for (int j = 0; j < 4; ++j) {
    unsigned short hb = f2bf(v[j]);
    h[j] = hb;
    l[j] = f2bf(v[j] - bf2f(hb));
  }
  ((u16x4*)oh)[i] = h;
  ((u16x4*)ol)[i] = l;
}

// ---------------- transpose + cast: (R,C) f32 -> (C,R) bf16 ----------------
__global__ void tcast_kernel(const float* __restrict__ in,
                             unsigned short* __restrict__ out, int R, int C) {
  int i = blockIdx.x * blockDim.x + threadIdx.x;
  if (i >= R * C) return;
  int r = i / C, c = i % C;
  out[(size_t)c * R + r] = f2bf(in[i]);
}

// ---------------- transpose + split cast: (R,C) f32 -> (C,R) hi/lo bf16 ----------------
__global__ void tcast_split_kernel(const float* __restrict__ in,
                                   unsigned short* __restrict__ oh,
                                   unsigned short* __restrict__ ol, int R, int C) {
  int i = blockIdx.x * blockDim.x + threadIdx.x;
  if (i >= R * C) return;
  int r = i / C, c = i % C;
  float v = in[i];
  unsigned short hb = f2bf(v);
  oh[(size_t)c * R + r] = hb;
  ol[(size_t)c * R + r] = f2bf(v - bf2f(hb));
}

// ---------------- f gate: one wave per token row (pure f32) ----------------
__global__ __launch_bounds__(256) void fgate_kernel(const float* __restrict__ x,
                                                    const float* __restrict__ Wf,
                                                    const float* __restrict__ bfv,
                                                    float* __restrict__ fbuf) {
  int wid = (blockIdx.x * blockDim.x + threadIdx.x) >> 6;  // token row 0..4095
  int lane = threadIdx.x & 63;
  const float* xr = x + (size_t)wid * 1024;
  float acc[8] = {0.f, 0.f, 0.f, 0.f, 0.f, 0.f, 0.f, 0.f};
#pragma unroll 4
  for (int it = 0; it < 16; ++it) {
    int d = it * 64 + lane;
    float xv = xr[d];
    f32x4 w0 = *(const f32x4*)(Wf + (size_t)d * 8);
    f32x4 w1 = *(const f32x4*)(Wf + (size_t)d * 8 + 4);
    acc[0] += xv * w0[0]; acc[1] += xv * w0[1];
    acc[2] += xv * w0[2]; acc[3] += xv * w0[3];
    acc[4] += xv * w1[0]; acc[5] += xv * w1[1];
    acc[6] += xv * w1[2]; acc[7] += xv * w1[3];
  }
#pragma unroll
  for (int n = 0; n < 8; ++n) {
#pragma unroll
    for (int m = 1; m < 64; m <<= 1) acc[n] += __shfl_xor(acc[n], m, 64);
  }
  if (lane == 0) {
#pragma unroll
    for (int n = 0; n < 8; ++n)
      fbuf[(size_t)wid * 8 + n] = sigmoidf_fast(acc[n] + bfv[n]);
  }
}

// ---------------- causal depthwise conv (KC=4) + SiLU, all 3 tensors ----------------
__global__ void conv_silu_kernel(const float* __restrict__ pre,
                                 const float* __restrict__ cwq,
                                 const float* __restrict__ cwk,
                                 const float* __restrict__ cwv,
                                 float* __restrict__ outb) {
  int i = blockIdx.x * blockDim.x + threadIdx.x;  // B*L*512
  int which = blockIdx.y;
  const float* cw = (which == 0) ? cwq : (which == 1) ? cwk : cwv;
  const float* p = pre + (size_t)which * 2097152 + i;
  int c = i & 511;
  int l = (i >> 9) & 1023;
  float w0 = cw[c * 4 + 0], w1 = cw[c * 4 + 1], w2 = cw[c * 4 + 2], w3 = cw[c * 4 + 3];
  float acc = w3 * p[0];
  if (l >= 1) acc += w2 * p[-512];
  if (l >= 2) acc += w1 * p[-1024];
  if (l >= 3) acc += w0 * p[-1536];
  outb[(size_t)which * 2097152 + i] = acc * sigmoidf_fast(acc);
}

// ---------------- plain bf16 MFMA GEMM: C(M,Nd) = A * Bt^T ----------------
__global__ __launch_bounds__(256) void gemm_bf16_kernel(
    const unsigned short* __restrict__ A, const unsigned short* __restrict__ Bt,
    float* __restrict__ C, int Kd, int Nd, size_t BtStride, size_t CStride) {
  __shared__ unsigned short Ash[128][40];
  __shared__ unsigned short Bsh[128][40];
  const int tid = threadIdx.x;
  const int wave = tid >> 6, lane = tid & 63;
  const int g = lane >> 4, lr = lane & 15;
  const int m0 = blockIdx.x * 128, n0 = blockIdx.y * 128;
  const unsigned short* Bz = Bt + blockIdx.z * BtStride;
  float* Cz = C + blockIdx.z * CStride;
  const int wm = (wave >> 1) * 64, wn = (wave & 1) * 64;

  f32x4 acc[4][4];
#pragma unroll
  for (int a = 0; a < 4; ++a)
#pragma unroll
    for (int bq = 0; bq < 4; ++bq) acc[a][bq] = (f32x4){0.f, 0.f, 0.f, 0.f};

  for (int k0 = 0; k0 < Kd; k0 += 32) {
#pragma unroll
    for (int it = 0; it < 2; ++it) {
      int cch = tid + 256 * it;
      int r = cch >> 2, cc = cch & 3;
      *(i32x4*)&Ash[r][cc * 8] = *(const i32x4*)(A + (size_t)(m0 + r) * Kd + k0 + cc * 8);
      *(i32x4*)&Bsh[r][cc * 8] = *(const i32x4*)(Bz + (size_t)(n0 + r) * Kd + k0 + cc * 8);
    }
    __syncthreads();
    short8 af[4], bfr[4];
#pragma unroll
    for (int mt = 0; mt < 4; ++mt) af[mt] = *(const short8*)&Ash[wm + mt * 16 + lr][g * 8];
#pragma unroll
    for (int nt = 0; nt < 4; ++nt) bfr[nt] = *(const short8*)&Bsh[wn + nt * 16 + lr][g * 8];
#pragma unroll
    for (int mt = 0; mt < 4; ++mt)
#pragma unroll
      for (int nt = 0; nt < 4; ++nt)
        acc[mt][nt] = __builtin_amdgcn_mfma_f32_16x16x32_bf16(af[mt], bfr[nt], acc[mt][nt], 0, 0, 0);
    __syncthreads();
  }
#pragma unroll
  for (int mt = 0; mt < 4; ++mt)
#pragma unroll
    for (int nt = 0; nt < 4; ++nt)
#pragma unroll
      for (int r = 0; r < 4; ++r) {
        int m = m0 + wm + mt * 16 + g * 4 + r;
        int n = n0 + wn + nt * 16 + lr;
        Cz[(size_t)m * Nd + n] = acc[mt][nt][r];
      }
}

// ---------------- split-bf16 (3-term f32-emulation) GEMM ----------------
__global__ __launch_bounds__(256) void gemm_split_kernel(
    const unsigned short* __restrict__ Ah, const unsigned short* __restrict__ Al,
    const unsigned short* __restrict__ Bth, const unsigned short* __restrict__ Btl,
    float* __restrict__ C, int Kd, int Nd, size_t BtStride, size_t CStride) {
  __shared__ unsigned short AshH[128][40];
  __shared__ unsigned short AshL[128][40];
  __shared__ unsigned short BshH[128][40];
  __shared__ unsigned short BshL[128][40];
  const int tid = threadIdx.x;
  const int wave = tid >> 6, lane = tid & 63;
  const int g = lane >> 4, lr = lane & 15;
  const int m0 = blockIdx.x * 128, n0 = blockIdx.y * 128;
  const unsigned short* Bzh = Bth + blockIdx.z * BtStride;
  const unsigned short* Bzl = Btl + blockIdx.z * BtStride;
  float* Cz = C + blockIdx.z * CStride;
  const int wm = (wave >> 1) * 64, wn = (wave & 1) * 64;

  f32x4 acc[4][4];
#pragma unroll
  for (int a = 0; a < 4; ++a)
#pragma unroll
    for (int bq = 0; bq < 4; ++bq) acc[a][bq] = (f32x4){0.f, 0.f, 0.f, 0.f};

  for (int k0 = 0; k0 < Kd; k0 += 32) {
#pragma unroll
    for (int it = 0; it < 2; ++it) {
      int cch = tid + 256 * it;
      int r = cch >> 2, cc = cch & 3;
      size_t ao = (size_t)(m0 + r) * Kd + k0 + cc * 8;
      size_t bo = (size_t)(n0 + r) * Kd + k0 + cc * 8;
      *(i32x4*)&AshH[r][cc * 8] = *(const i32x4*)(Ah + ao);
      *(i32x4*)&AshL[r][cc * 8] = *(const i32x4*)(Al + ao);
      *(i32x4*)&BshH[r][cc * 8] = *(const i32x4*)(Bzh + bo);
      *(i32x4*)&BshL[r][cc * 8] = *(const i32x4*)(Bzl + bo);
    }
    __syncthreads();
    short8 afh[4], afl[4], bfh[4], bfl[4];
#pragma unroll
    for (int mt = 0; mt < 4; ++mt) {
      afh[mt] = *(const short8*)&AshH[wm + mt * 16 + lr][g * 8];
      afl[mt] = *(const short8*)&AshL[wm + mt * 16 + lr][g * 8];
    }
#pragma unroll
    for (int nt = 0; nt < 4; ++nt) {
      bfh[nt] = *(const short8*)&BshH[wn + nt * 16 + lr][g * 8];
      bfl[nt] = *(const short8*)&BshL[wn + nt * 16 + lr][g * 8];
    }
#pragma unroll
    for (int mt = 0; mt < 4; ++mt)
#pragma unroll
      for (int nt = 0; nt < 4; ++nt) {
        f32x4 a = acc[mt][nt];
        a = __builtin_amdgcn_mfma_f32_16x16x32_bf16(afl[mt], bfh[nt], a, 0, 0, 0);
        a = __builtin_amdgcn_mfma_f32_16x16x32_bf16(afh[mt], bfl[nt], a, 0, 0, 0);
        a = __builtin_amdgcn_mfma_f32_16x16x32_bf16(afh[mt], bfh[nt], a, 0, 0, 0);
        acc[mt][nt] = a;
      }
    __syncthreads();
  }
#pragma unroll
  for (int mt = 0; mt < 4; ++mt)
#pragma unroll
    for (int nt = 0; nt < 4; ++nt)
#pragma unroll
      for (int r = 0; r < 4; ++r) {
        int m = m0 + wm + mt * 16 + g * 4 + r;
        int n = n0 + wn + nt * 16 + lr;
        Cz[(size_t)m * Nd + n] = acc[mt][nt][r];
      }
}

// ---------------- recurrent scan: k-slice split ----------------
// Each k-row of H evolves independently (cand[k][w] = tanh(sum_v H[k][v]W[v][w]
// + k_t[k]v_t[w]); blend is per-element). Split each (b,n) chain into 4 k-slices
// of 16 rows -> 128 blocks x 256 thr (4 waves), 1 wave/SIMD. Per wave: one 16x16
// C-tile (rows w in [16*wave,+16), cols k=lr), 6 MFMAs, 4 H f32/lane.
// y needs sum over k: each slice writes bf16 y-partials; ysum_kernel folds 4.
// Slice H planes (ping-pong): row k(local)=lr at byte lr*128, elem v at byte
// (2v) ^ ((lr&7)<<4)   [same verified swizzle, kq -> lr].
__global__ __launch_bounds__(256) void scan_kernel(
    const float* __restrict__ qbuf, const float* __restrict__ kbuf,
    const float* __restrict__ vbuf, const float* __restrict__ fbuf,
    const float* __restrict__ W, unsigned short* __restrict__ ypart,
    float* __restrict__ Hout) {
  const int tid = threadIdx.x;
  const int wave = tid >> 6, lane = tid & 63;
  const int g = lane >> 4, lr = lane & 15;
  const int bz = blockIdx.x;
  const int chain = bz >> 2, ks = bz & 3;
  const int b = chain >> 3, n = chain & 7;
  const int swz = (lr & 7) << 4;

  __shared__ unsigned short Hh[2][1024];   // 16x64 bf16 hi, ping-pong (2 KB each)
  __shared__ unsigned short Hl[2][1024];   // lo planes
  __shared__ float stage[2][16][192];      // 24 KB
  __shared__ float fs[2][16];
  __shared__ float yst[16][64];            // 4 KB y chunk buffer (f32)

  // zero plane 0 (H_0 = 0): 512 u32 per plane
  for (int i = tid; i < 512; i += 256) {
    ((unsigned*)Hh[0])[i] = 0u;
    ((unsigned*)Hl[0])[i] = 0u;
  }

  // W^T split hi/lo fragments: A[m=lr][k-chunk], m = w = 16*wave + lr
  const float* Wn = W + (size_t)n * 4096;
  short8 Af[2], Alw[2];
#pragma unroll
  for (int s = 0; s < 2; ++s) {
    int wcol = wave * 16 + lr;
    short8 ah, al;
#pragma unroll
    for (int j = 0; j < 8; ++j) {
      float wv = Wn[(size_t)(s * 32 + g * 8 + j) * 64 + wcol];
      unsigned short hb = f2bf(wv);
      ah[j] = (short)hb;
      al[j] = (short)f2bf(wv - bf2f(hb));
    }
    Af[s] = ah; Alw[s] = al;
  }

  // chunk staging: 16 steps x 192 floats = 768 f32x4 by 256 threads (3 each)
  auto stage_chunk = [&](int c, int buf) {
#pragma unroll
    for (int i = 0; i < 3; ++i) {
      int fi = tid + i * 256;
      int st = fi / 48, un = fi - st * 48;
      const float* basep = (un < 16) ? qbuf : (un < 32) ? kbuf : vbuf;
      f32x4 val = *(const f32x4*)(basep + (size_t)(b * 1024 + c * 16 + st) * 512 +
                                  n * 64 + (un & 15) * 4);
      *(f32x4*)&stage[buf][st][un * 4] = val;
    }
    if (tid < 16) fs[buf][tid] = fbuf[(size_t)(b * 1024 + c * 16 + tid) * 8 + n];
  };

  f32x4 HA = (f32x4){0.f, 0.f, 0.f, 0.f};  // H[ks*16+lr][w=16*wave+4g+r], f32 master
  int sb = 0, pp = 0;

  stage_chunk(0, 0);
  __syncthreads();

  const f32x4 zf = (f32x4){0.f, 0.f, 0.f, 0.f};
  const int bo0 = (16 * g) ^ swz;               // B-frag chunk 0 (v = g*8..)
  const int bo1 = (64 + 16 * g) ^ swz;          // chunk 1 (v = 32 + g*8..)
  const int wo = (32 * wave + 8 * g) ^ swz;     // H-write: 4 w at 16*wave+4g
  const float K2L2E = 2.885390081777927f;       // 2*log2(e)
  const int kg = ks * 16 + lr;                  // global k row of this lane

  for (int c = 0; c < 64; ++c) {
    if (c < 63) stage_chunk(c + 1, sb ^ 1);
    for (int tl = 0; tl < 16; ++tl) {
      const float* srow = &stage[sb][tl][0];

      // B-frags of H_t slice from plane pp (row lr, hi+lo, both v-chunks)
      const char* hrh = (const char*)(Hh[pp] + lr * 64);
      const char* hrl = (const char*)(Hl[pp] + lr * 64);
      short8 Bh0 = *(const short8*)(hrh + bo0);
      short8 Bh1 = *(const short8*)(hrh + bo1);
      short8 Bl0 = *(const short8*)(hrl + bo0);
      short8 Bl1 = *(const short8*)(hrl + bo1);

      // 6 MFMAs: 3-term split, 2 independent chains of 3
      f32x4 cX = __builtin_amdgcn_mfma_f32_16x16x32_bf16(Alw[0], Bh0, zf, 0, 0, 0);
      f32x4 cY = __builtin_amdgcn_mfma_f32_16x16x32_bf16(Alw[1], Bh1, zf, 0, 0, 0);
      cX = __builtin_amdgcn_mfma_f32_16x16x32_bf16(Af[0], Bl0, cX, 0, 0, 0);
      cY = __builtin_amdgcn_mfma_f32_16x16x32_bf16(Af[1], Bl1, cY, 0, 0, 0);
      cX = __builtin_amdgcn_mfma_f32_16x16x32_bf16(Af[0], Bh0, cX, 0, 0, 0);
      cY = __builtin_amdgcn_mfma_f32_16x16x32_bf16(Af[1], Bh1, cY, 0, 0, 0);

      float kval = srow[64 + kg];
      f32x4 vv = *(const f32x4*)(srow + 128 + wave * 16 + 4 * g);
      float fc = fs[sb][tl];
      f32x4 a0 = cX + cY;

      // tanh (exp2-fused, overflow-safe) + gate blend -> H_{t+1} (f32, exact)
#pragma unroll
      for (int r = 0; r < 4; ++r) {
        float arg = fmaf(kval, vv[r], a0[r]);
        float cd = fmaf(-2.f, __builtin_amdgcn_rcpf(1.f + __builtin_amdgcn_exp2f(arg * K2L2E)), 1.f);
        HA[r] = fmaf(fc, HA[r] - cd, cd);
      }

      // y slice-partials: sum over the 16 k-rows (= 16 lr lanes) via DPP.
      // Each wave owns disjoint w -> no cross-wave reduction needed.
      {
        float qs = srow[kg];
        float y0 = row_sum16(qs * HA[0]);
        float y1 = row_sum16(qs * HA[1]);
        float y2 = row_sum16(qs * HA[2]);
        float y3 = row_sum16(qs * HA[3]);
        if (lr == 15)
          *(f32x4*)&yst[tl][wave * 16 + 4 * g] = (f32x4){y0, y1, y2, y3};
      }

      // pack (cvt_pk) and write H_{t+1} to plane pp^1
      {
        char* hwh = (char*)(Hh[pp ^ 1] + lr * 64);
        char* hwl = (char*)(Hl[pp ^ 1] + lr * 64);
        unsigned ph0 = cvt_pk_bf16(HA[0], HA[1]);
        unsigned ph1 = cvt_pk_bf16(HA[2], HA[3]);
        float r0 = HA[0] - __builtin_bit_cast(float, ph0 << 16);
        float r1 = HA[1] - __builtin_bit_cast(float, ph0 & 0xFFFF0000u);
        float r2 = HA[2] - __builtin_bit_cast(float, ph1 << 16);
        float r3 = HA[3] - __builtin_bit_cast(float, ph1 & 0xFFFF0000u);
        *(u32x2*)(hwh + wo) = (u32x2){ph0, ph1};
        *(u32x2*)(hwl + wo) = (u32x2){cvt_pk_bf16(r0, r1), cvt_pk_bf16(r2, r3)};
      }

      __syncthreads();   // single barrier: plane pp^1 + (for chunk end) yst visible
      pp ^= 1;
    }

    // flush y slice-partials for this chunk (bf16), coalesced
    for (int i = tid; i < 1024; i += 256) {
      int tl2 = i >> 6, w = i & 63;
      ypart[(size_t)ks * 2097152 +
            (size_t)(b * 1024 + c * 16 + tl2) * 512 + n * 64 + w] = f2bf(yst[tl2][w]);
    }
    __syncthreads();   // protect yst reuse by next chunk
    sb ^= 1;
  }

  // H_final (f32 master): this slice owns rows ks*16..ks*16+16
  float* Ho = Hout + (size_t)(b * 8 + n) * 4096;
  *(f32x4*)&Ho[(size_t)kg * 64 + wave * 16 + g * 4] = HA;
}

// ---------------- sum 4 y slice-partials -> bf16 y ----------------
__global__ void ysum_kernel(const unsigned short* __restrict__ yp,
                            unsigned short* __restrict__ yb) {
  int i = blockIdx.x * 256 + threadIdx.x;   // x4 elems, 524288 threads total
  u16x4 s0 = ((const u16x4*)yp)[i];
  u16x4 s1 = ((const u16x4*)(yp + 2097152))[i];
  u16x4 s2 = ((const u16x4*)(yp + 2 * 2097152))[i];
  u16x4 s3 = ((const u16x4*)(yp + 3 * 2097152))[i];
  u16x4 o;
#pragma unroll
  for (int j = 0; j < 4; ++j)
    o[j] = f2bf(bf2f(s0[j]) + bf2f(s1[j]) + bf2f(s2[j]) + bf2f(s3[j]));
  ((u16x4*)yb)[i] = o;
}

// ---------------- launch ----------------
extern "C" void kernel_launch(void* const* d_in, const int* in_sizes, int n_in,
                              void* d_out, int out_size, void* d_ws, size_t ws_size,
                              hipStream_t stream) {
  const float* x   = (const float*)d_in[0];
  const float* Wq  = (const float*)d_in[1];
  const float* Wk  = (const float*)d_in[2];
  const float* Wv  = (const float*)d_in[3];
  const float* Wf  = (const float*)d_in[4];
  const float* bfv = (const float*)d_in[5];
  const float* cwq = (const float*)d_in[6];
  const float* cwk = (const float*)d_in[7];
  const float* cwv = (const float*)d_in[8];
  const float* W   = (const float*)d_in[9];
  const float* Wo  = (const float*)d_in[10];
  float* outp = (float*)d_out;

  char* ws = (char*)d_ws;
  size_t off = 0;
  auto alloc = [&](size_t bytes) {
    char* pp = ws + off;
    off = (off + bytes + 255) & ~(size_t)255;
    return pp;
  };
  unsigned short* xbh  = (unsigned short*)alloc((size_t)4194304 * 2);
  unsigned short* xbl  = (unsigned short*)alloc((size_t)4194304 * 2);
  unsigned short* wtbh = (unsigned short*)alloc((size_t)3 * 524288 * 2);
  unsigned short* wtbl = (unsigned short*)alloc((size_t)3 * 524288 * 2);
  float* pre  = (float*)alloc((size_t)3 * 2097152 * 4);   // also aliased: y partials (16 MB)
  float* qkv  = (float*)alloc((size_t)3 * 2097152 * 4);
  float* fbuf = (float*)alloc((size_t)32768 * 4);
  unsigned short* yb  = (unsigned short*)alloc((size_t)2097152 * 2);
  unsigned short* wot = (unsigned short*)alloc((size_t)524288 * 2);
  unsigned short* ypart = (unsigned short*)pre;  // pre is dead after conv_silu

  // casts / transposes (split hi/lo for the amplified paths)
  cast_split_kernel<<<4096, 256, 0, stream>>>(x, xbh, xbl, 1048576);
  tcast_split_kernel<<<2048, 256, 0, stream>>>(Wq, wtbh, wtbl, 1024, 512);
  tcast_split_kernel<<<2048, 256, 0, stream>>>(Wk, wtbh + 524288, wtbl + 524288, 1024, 512);
  tcast_split_kernel<<<2048, 256, 0, stream>>>(Wv, wtbh + 2 * 524288, wtbl + 2 * 524288, 1024, 512);
  // gate
  fgate_kernel<<<1024, 256, 0, stream>>>(x, Wf, bfv, fbuf);
  // q pre-activation: plain bf16 (un-amplified path)
  dim3 gq(32, 4, 1);
  gemm_bf16_kernel<<<gq, 256, 0, stream>>>(xbh, wtbh, pre, 1024, 512,
                                           (size_t)0, (size_t)0);
  // k,v pre-activations: split-bf16 (amplified path)
  dim3 gkv(32, 4, 2);
  gemm_split_kernel<<<gkv, 256, 0, stream>>>(xbh, xbl, wtbh + 524288, wtbl + 524288,
                                             pre + 2097152, 1024, 512,
                                             (size_t)524288, (size_t)2097152);
  // conv + silu (all three in one launch); pre is dead afterwards
  dim3 gc(8192, 3, 1);
  conv_silu_kernel<<<gc, 256, 0, stream>>>(pre, cwq, cwk, cwv, qkv);
  // recurrent scan: 128 blocks (32 chains x 4 k-slices) x 256 threads
  scan_kernel<<<128, 256, 0, stream>>>(qkv, qkv + 2097152, qkv + 2 * 2097152, fbuf, W,
                                       ypart, outp + 4194304);
  // fold slice partials -> yb (bf16)
  ysum_kernel<<<2048, 256, 0, stream>>>(ypart, yb);
  // output projection
  tcast_kernel<<<2048, 256, 0, stream>>>(Wo, wot, 512, 1024);
  dim3 g2(32, 8, 1);
  gemm_bf16_kernel<<<g2, 256, 0, stream>>>(yb, wot, outp, 512, 1024, (size_t)0, (size_t)0);
}